// Round 8
// baseline (1841.932 us; speedup 1.0000x reference)
//
#include <hip/hip_runtime.h>
#include <hip/hip_bf16.h>

// LPKT+ forward. B=32, S=128, C=256, K=128, DC=128, T=127 scan steps.
//
//  K1: AL = [eq|eut]@W1a^T + b1 + correct*rs1c ; pre5 = eq@W5q^T + b5
//  K2: pre23 = [AL[t-1]|it|AL[t]] @ [W2a|W3a]^T + b ; pre4 = it@W4i^T + b4
//  K3 (scan): 64 blocks = 32 batches x 2 c-halves; 512 threads (8 waves =
//      4 j-quarters x 2 col-halves of the block's 128 columns). h fp32 in
//      registers + bf16 shadow in LDS (dbuf, subtiled, conflict-free).
//      Per step the two half-blocks exchange ONLY the 128-float h_tilde
//      partial via L2 (write-once per-tau slots + release/acquire flags,
//      flags memset per launch). 2 barriers/step.
//  K4: batched y = mean_j sigmoid(pre5 + W5h @ ht_hist).

typedef __bf16 bf16x8 __attribute__((ext_vector_type(8)));
typedef __bf16 bf16x4 __attribute__((ext_vector_type(4)));
typedef float f32x4 __attribute__((ext_vector_type(4)));

#define HBUF 16384               // elems per h-shadow buffer (128x128 bf16)

__device__ __forceinline__ float sigmf(float x){
  return __builtin_amdgcn_rcpf(1.0f + __expf(-x));
}

__device__ __forceinline__ bf16x8 cvt8(float4 a, float4 b){
  bf16x8 r;
  r[0]=(__bf16)a.x; r[1]=(__bf16)a.y; r[2]=(__bf16)a.z; r[3]=(__bf16)a.w;
  r[4]=(__bf16)b.x; r[5]=(__bf16)b.y; r[6]=(__bf16)b.z; r[7]=(__bf16)b.w;
  return r;
}

// hi/lo bf16 split of 8 fp32 values (fp32-grade MFMA input)
__device__ __forceinline__ void mk_hilo(float4 a, float4 b, bf16x8& hi, bf16x8& lo){
  float v[8] = {a.x,a.y,a.z,a.w,b.x,b.y,b.z,b.w};
  #pragma unroll
  for (int i = 0; i < 8; i++){
    __bf16 h = (__bf16)v[i];
    hi[i] = h;
    lo[i] = (__bf16)(v[i] - (float)h);
  }
}

__device__ __forceinline__ f32x4 mfma16(bf16x8 a, bf16x8 b, f32x4 c){
  return __builtin_amdgcn_mfma_f32_16x16x32_bf16(a, b, c, 0, 0, 0);
}

// sum over each row of 16 lanes via DPP row_shr (VALU pipe, not LDS).
// Result valid in lane la==15 of each row.
__device__ __forceinline__ float dpp_sum16(float v){
  int x;
  x = __builtin_amdgcn_update_dpp(0, __builtin_bit_cast(int, v), 0x111, 0xf, 0xf, true);
  v += __builtin_bit_cast(float, x);
  x = __builtin_amdgcn_update_dpp(0, __builtin_bit_cast(int, v), 0x112, 0xf, 0xf, true);
  v += __builtin_bit_cast(float, x);
  x = __builtin_amdgcn_update_dpp(0, __builtin_bit_cast(int, v), 0x114, 0xf, 0xf, true);
  v += __builtin_bit_cast(float, x);
  x = __builtin_amdgcn_update_dpp(0, __builtin_bit_cast(int, v), 0x118, 0xf, 0xf, true);
  v += __builtin_bit_cast(float, x);
  return v;
}

__device__ __forceinline__ void red16(f32x4& r){
  r[0] = dpp_sum16(r[0]);
  r[1] = dpp_sum16(r[1]);
  r[2] = dpp_sum16(r[2]);
  r[3] = dpp_sum16(r[3]);
}

// ---------------- K1 ----------------
__global__ __launch_bounds__(256) void k1_al(
    const int* __restrict__ qseq, const int* __restrict__ utseq,
    const float* __restrict__ corr,
    const float* __restrict__ Eq, const float* __restrict__ Eut,
    const float* __restrict__ W1, const float* __restrict__ b1,
    const float* __restrict__ W5, const float* __restrict__ b5,
    float* __restrict__ AL, float* __restrict__ pre5)
{
  __shared__ __bf16 inA[64*256];
  __shared__ float corrs[64];
  __shared__ float b1s[128], b5s[128], rsp[256];
  const int tid = threadIdx.x, blk = blockIdx.x;
  if (tid < 128){ b1s[tid]=b1[tid]; b5s[tid]=b5[tid]; }
  { // rs1c partial sums
    int j = tid & 127, hf = tid >> 7;
    const float* p = W1 + j*384 + 256 + hf*64;
    float s = 0.f;
    for (int i = 0; i < 64; i++) s += p[i];
    rsp[tid] = s;
  }
  {
    int r = tid >> 2, seg = tid & 3;
    int R = blk*64 + r;
    int qi = qseq[R], ui = utseq[R];
    if (seg == 0) corrs[r] = corr[R];
    for (int i = 0; i < 64; i++){
      int col = seg*64 + i;
      float v = (col < 128) ? Eq[qi*128 + col] : Eut[ui*128 + (col-128)];
      inA[((r*256 + col) ^ ((r&7)<<3))] = (__bf16)v;
    }
  }
  __syncthreads();
  const int w = tid >> 6, lane = tid & 63;
  const int la = lane & 15, g = lane >> 4;
  const int rbase = w*16;
  bf16x8 af[8];
  #pragma unroll
  for (int kt = 0; kt < 8; kt++){
    int idx = ((rbase+la)*256 + kt*32 + g*8) ^ ((la&7)<<3);
    af[kt] = *(const bf16x8*)&inA[idx];
  }
  for (int jt = 0; jt < 8; jt++){
    f32x4 acc = {0.f,0.f,0.f,0.f};
    const float* Wb = W1 + (jt*16+la)*384;
    #pragma unroll
    for (int kt = 0; kt < 8; kt++){
      const float* p = Wb + kt*32 + g*8;
      acc = mfma16(af[kt], cvt8(*(const float4*)p, *(const float4*)(p+4)), acc);
    }
    int j = jt*16 + la;
    float rsj = rsp[j] + rsp[j+128];
    #pragma unroll
    for (int rr = 0; rr < 4; rr++){
      int row = rbase + g*4 + rr;
      int R = blk*64 + row;
      AL[R*128 + j] = acc[rr] + b1s[j] + corrs[row]*rsj;
    }
  }
  for (int jt = 0; jt < 8; jt++){
    f32x4 acc = {0.f,0.f,0.f,0.f};
    const float* Wb = W5 + (jt*16+la)*256;
    #pragma unroll
    for (int kt = 0; kt < 4; kt++){
      const float* p = Wb + kt*32 + g*8;
      acc = mfma16(af[kt], cvt8(*(const float4*)p, *(const float4*)(p+4)), acc);
    }
    int j = jt*16 + la;
    #pragma unroll
    for (int rr = 0; rr < 4; rr++){
      int row = rbase + g*4 + rr;
      int R = blk*64 + row;
      pre5[R*128 + j] = acc[rr] + b5s[j];
    }
  }
}

// ---------------- K2 ----------------
__global__ __launch_bounds__(256) void k2_pre(
    const int* __restrict__ itseq, const float* __restrict__ Eit,
    const float* __restrict__ AL,
    const float* __restrict__ W2, const float* __restrict__ W3,
    const float* __restrict__ W4,
    const float* __restrict__ b2, const float* __restrict__ b3,
    const float* __restrict__ b4,
    float* __restrict__ pre23, float* __restrict__ pre4)
{
  __shared__ __bf16 inA[64*384];
  __shared__ int obase[64];
  __shared__ float b2s[128], b3s[128], b4s[128];
  const int tid = threadIdx.x, blk = blockIdx.x;
  if (tid < 128){ b2s[tid]=b2[tid]; b3s[tid]=b3[tid]; b4s[tid]=b4[tid]; }
  {
    int r = tid >> 2, seg = tid & 3;
    int R = blk*64 + r;
    bool valid = (R < 4064);
    int b_ = R / 127, tau = R % 127;
    if (seg == 0) obase[r] = valid ? (b_*127 + tau) : -1;
    int itv = valid ? itseq[b_*128 + tau] : 0;
    for (int i = 0; i < 96; i++){
      int col = seg*96 + i;
      float v = 0.f;
      if (valid){
        if (col < 128)      v = (tau > 0) ? AL[(b_*128 + tau-1)*128 + col] : 0.f;
        else if (col < 256) v = Eit[itv*128 + (col-128)];
        else                v = AL[(b_*128 + tau)*128 + (col-256)];
      }
      inA[((r*384 + col) ^ ((r&7)<<3))] = (__bf16)v;
    }
  }
  __syncthreads();
  const int w = tid >> 6, lane = tid & 63;
  const int la = lane & 15, g = lane >> 4;
  const int rbase = w*16;
  bf16x8 af[12];
  #pragma unroll
  for (int kt = 0; kt < 12; kt++){
    int idx = ((rbase+la)*384 + kt*32 + g*8) ^ ((la&7)<<3);
    af[kt] = *(const bf16x8*)&inA[idx];
  }
  for (int jt = 0; jt < 16; jt++){
    f32x4 acc = {0.f,0.f,0.f,0.f};
    int j = jt*16 + la;
    const float* Wb = (j < 128) ? (W2 + j*512) : (W3 + (j-128)*512);
    #pragma unroll
    for (int kt = 0; kt < 12; kt++){
      const float* p = Wb + kt*32 + g*8;
      acc = mfma16(af[kt], cvt8(*(const float4*)p, *(const float4*)(p+4)), acc);
    }
    float bias = (j < 128) ? b2s[j] : b3s[j-128];
    #pragma unroll
    for (int rr = 0; rr < 4; rr++){
      int row = rbase + g*4 + rr;
      int ob = obase[row];
      if (ob >= 0) pre23[ob*256 + j] = acc[rr] + bias;
    }
  }
  for (int jt = 0; jt < 8; jt++){
    f32x4 acc = {0.f,0.f,0.f,0.f};
    int j = jt*16 + la;
    const float* Wb = W4 + j*384 + 256;
    #pragma unroll
    for (int kk = 0; kk < 4; kk++){
      const float* p = Wb + kk*32 + g*8;
      acc = mfma16(af[4+kk], cvt8(*(const float4*)p, *(const float4*)(p+4)), acc);
    }
    #pragma unroll
    for (int rr = 0; rr < 4; rr++){
      int row = rbase + g*4 + rr;
      int ob = obase[row];
      if (ob >= 0) pre4[ob*128 + j] = acc[rr] + b4s[j];
    }
  }
}

// ---------------- K3: scan, 64 blocks x 512 threads ----------------
// LDS floats: hB bf16 2x16384 = 16384 f | htb0[2][128] 256 | htb1[2][128] 256 |
//   LGb 128 | LGh(bf16) 64 | qeb[3][256] 768 | p23L[2][256] 512 |
//   p4L[2][128] 256 | qsl(int) 128  => 18752 f = 75008 B
#define SCAN_LDS_BYTES (18752*4)

__global__ __launch_bounds__(512, 2) void lpkt_scan(
    const float* __restrict__ qmat, const int* __restrict__ qseq,
    const float* __restrict__ h0,
    const float* __restrict__ W2, const float* __restrict__ W3,
    const float* __restrict__ W4,
    const float* __restrict__ pre23, const float* __restrict__ pre4,
    float* __restrict__ hist, float* __restrict__ xbuf, int* __restrict__ flags)
{
  extern __shared__ float lds[];
  __bf16* hB   = (__bf16*)lds;            // 2 x subtiled 128x128 (own c-half)
  float*  htb0 = lds + 16384;             // [2][128] ch partials
  float*  htb1 = lds + 16640;             // [2][128]
  float*  LGb  = lds + 16896;             // fp32 LG
  __bf16* LGh  = (__bf16*)(lds + 17024);  // bf16 LG
  float*  qeb  = lds + 17088;             // [3][256]
  float*  p23L = lds + 17856;             // [2][256]
  float*  p4L  = lds + 18368;             // [2][128]
  int*    qsl  = (int*)(lds + 18624);

  const int tid  = threadIdx.x;
  const int bid  = blockIdx.x;
  const int half = bid >> 5;           // c-half of this block
  const int b    = bid & 31;           // batch  (pair (b, b+32) -> same XCD)
  const int lane = tid & 63;
  const int w    = tid >> 6;           // 8 waves
  const int la   = lane & 15, g = lane >> 4;
  const int jq   = w & 3;              // j-quarter of k-dim outputs
  const int ch   = w >> 2;             // 64-col half of this block's 128 cols

  // exchange buffers (write-once per-tau slots; flags memset each launch)
  float* xmine = xbuf + ((size_t)(b*2 + half))*128*128;
  const float* xpeer = xbuf + ((size_t)(b*2 + (half^1)))*128*128;
  int* fmine = flags + (b*2 + half)*128;
  const int* fpeer = flags + (b*2 + (half^1))*128;

  // ---- persistent register weight fragments (MFMA-A -> AGPR-friendly) ----
  bf16x8 af[2][4];                     // W4h rows (jq*2+jj)*16+la
  bf16x8 af4l[2][4];                   // W4l rows (jq*2+jj)*16+la
  #pragma unroll
  for (int jj = 0; jj < 2; jj++){
    #pragma unroll
    for (int kt = 0; kt < 4; kt++){
      const float* ph = W4 + ((jq*2+jj)*16+la)*384 + kt*32 + g*8;
      const float* pl = W4 + ((jq*2+jj)*16+la)*384 + 128 + kt*32 + g*8;
      af[jj][kt]   = cvt8(*(const float4*)ph, *(const float4*)(ph+4));
      af4l[jj][kt] = cvt8(*(const float4*)pl, *(const float4*)(pl+4));
    }
  }
  bf16x8 af23[2][4];                   // W2h tile w, W3h tile w
  #pragma unroll
  for (int kt = 0; kt < 4; kt++){
    const float* p2 = W2 + (w*16+la)*512 + 384 + kt*32 + g*8;
    const float* p3 = W3 + (w*16+la)*512 + 384 + kt*32 + g*8;
    af23[0][kt] = cvt8(*(const float4*)p2, *(const float4*)(p2+4));
    af23[1][kt] = cvt8(*(const float4*)p3, *(const float4*)(p3+4));
  }

  // ---- precomputed LDS bases (local c index cl = ch*64+cg*16+la) ----
  // subtiled: elem(cl,k) -> ((cl>>4)*16 + (k>>3))*128 + (cl&15)*8 + (k&7)
  int rb[4], wb[4];
  #pragma unroll
  for (int cg = 0; cg < 4; cg++){
    const int cblk = ch*4 + cg;
    rb[cg] = cblk*2048 + g*128 + la*8;                          // + kt*512
    wb[cg] = cblk*2048 + jq*512 + (g>>1)*128 + la*8 + (g&1)*4;  // + jj*256
  }

  // ---- init staging ----
  if (tid < 128) qsl[tid] = qseq[b*128 + tid];
  __syncthreads();
  const float* pre23b = pre23 + b*127*256;
  const float* pre4b  = pre4  + b*127*128;
  if (tid < 64)       *(float4*)&qeb[tid*4] = *(const float4*)(qmat + (size_t)qsl[0]*256 + tid*4);
  else if (tid < 128) *(float4*)&qeb[256 + (tid-64)*4] = *(const float4*)(qmat + (size_t)qsl[1]*256 + (tid-64)*4);
  else if (tid < 192) *(float4*)&p23L[(tid-128)*4] = *(const float4*)(pre23b + (tid-128)*4);
  else if (tid < 224) *(float4*)&p4L[(tid-192)*4]  = *(const float4*)(pre4b  + (tid-192)*4);

  // h state (own c-half) -> registers + bf16 shadow buffer 0
  float4 hreg[4][2];
  #pragma unroll
  for (int cg = 0; cg < 4; cg++){
    const int c_ = half*128 + ch*64 + cg*16 + la;
    #pragma unroll
    for (int jj = 0; jj < 2; jj++){
      const int k0 = (jq*2+jj)*16 + g*4;
      float4 v = *(const float4*)(h0 + c_*128 + k0);
      hreg[cg][jj] = v;
      bf16x4 hb; hb[0]=(__bf16)v.x; hb[1]=(__bf16)v.y; hb[2]=(__bf16)v.z; hb[3]=(__bf16)v.w;
      *(bf16x4*)&hB[wb[cg] + jj*256] = hb;
    }
  }
  __syncthreads();
  // local partial of htilde0 over own c-half (DPP reduce, split ch stores)
  {
    f32x4 r0 = {0.f,0.f,0.f,0.f}, r1 = {0.f,0.f,0.f,0.f};
    #pragma unroll
    for (int cg = 0; cg < 4; cg++){
      const int c_ = half*128 + ch*64 + cg*16 + la;
      float q = qeb[c_];
      float4 h0v = hreg[cg][0], h1v = hreg[cg][1];
      r0[0] += q*h0v.x; r0[1] += q*h0v.y; r0[2] += q*h0v.z; r0[3] += q*h0v.w;
      r1[0] += q*h1v.x; r1[1] += q*h1v.y; r1[2] += q*h1v.z; r1[3] += q*h1v.w;
    }
    red16(r0); red16(r1);
    if (la == 15){
      float4 s0 = {r0[0],r0[1],r0[2],r0[3]};
      float4 s1 = {r1[0],r1[1],r1[2],r1[3]};
      *(float4*)&htb0[ch*128 + jq*32 + g*4]      = s0;
      *(float4*)&htb0[ch*128 + jq*32 + 16 + g*4] = s1;
    }
  }
  __syncthreads();

  int i0 = 0, i1 = 1, i2 = 2;          // qe triple-buffer rotation

  for (int tau = 0; tau < 127; tau++){
    float* htc = (tau & 1) ? htb1 : htb0;       // [2][128] local ch partials
    float* htn = (tau & 1) ? htb0 : htb1;
    float* qec = qeb + i0*256;
    float* qen = qeb + i1*256;
    float* qep = qeb + i2*256;
    const float* p23c = p23L + (tau & 1)*256;
    const float* p4c  = p4L  + (tau & 1)*128;
    const int roff = (tau & 1) ? HBUF : 0;
    const int woff = (tau & 1) ? 0 : HBUF;

    // ---- publish own h_tilde partial (state tau), poll partner's ----
    if (w == 0){
      if (lane < 32){
        float4 v0 = *(const float4*)&htc[lane*4];
        float4 v1 = *(const float4*)&htc[128 + lane*4];
        float4 v = {v0.x+v1.x, v0.y+v1.y, v0.z+v1.z, v0.w+v1.w};
        *(float4*)(xmine + (size_t)tau*128 + lane*4) = v;
      }
      __threadfence();
      if (lane == 0)
        __hip_atomic_store(&fmine[tau], 1, __ATOMIC_RELEASE, __HIP_MEMORY_SCOPE_AGENT);
    }
    {
      int it = 0;
      while (__hip_atomic_load(&fpeer[tau], __ATOMIC_ACQUIRE, __HIP_MEMORY_SCOPE_AGENT) == 0){
        __builtin_amdgcn_s_sleep(2);
        if (++it > (1 << 22)) break;   // bailout: never triggers in normal runs
      }
    }
    const float* xp = xpeer + (size_t)tau*128;

    // ---- P0: m23 via MFMA (hi/lo), LG on all lanes ----
    {
      bf16x8 xh[4], xl[4];
      #pragma unroll
      for (int kt = 0; kt < 4; kt++){
        int k0 = kt*32 + g*8;
        float4 a0 = *(const float4*)&htc[k0];
        float4 a1 = *(const float4*)&htc[k0+4];
        float4 b0 = *(const float4*)&htc[128 + k0];
        float4 b1v = *(const float4*)&htc[128 + k0+4];
        float4 c0 = *(const float4*)(xp + k0);
        float4 c1 = *(const float4*)(xp + k0 + 4);
        a0.x += b0.x + c0.x; a0.y += b0.y + c0.y;
        a0.z += b0.z + c0.z; a0.w += b0.w + c0.w;
        a1.x += b1v.x + c1.x; a1.y += b1v.y + c1.y;
        a1.z += b1v.z + c1.z; a1.w += b1v.w + c1.w;
        mk_hilo(a0, a1, xh[kt], xl[kt]);
      }
      f32x4 aLh = {0.f,0.f,0.f,0.f}, aLl = {0.f,0.f,0.f,0.f};
      f32x4 aGh = {0.f,0.f,0.f,0.f}, aGl = {0.f,0.f,0.f,0.f};
      #pragma unroll
      for (int kt = 0; kt < 4; kt++){
        aLh = mfma16(af23[0][kt], xh[kt], aLh);
        aLl = mfma16(af23[0][kt], xl[kt], aLl);
        aGh = mfma16(af23[1][kt], xh[kt], aGh);
        aGl = mfma16(af23[1][kt], xl[kt], aGl);
      }
      float4 lp4 = *(const float4*)&p23c[w*16 + g*4];
      float4 gp4 = *(const float4*)&p23c[128 + w*16 + g*4];
      float4 LG4;
      LG4.x = sigmf(aGh[0]+aGl[0]+gp4.x) * sigmf(2.f*(aLh[0]+aLl[0]+lp4.x));
      LG4.y = sigmf(aGh[1]+aGl[1]+gp4.y) * sigmf(2.f*(aLh[1]+aLl[1]+lp4.y));
      LG4.z = sigmf(aGh[2]+aGl[2]+gp4.z) * sigmf(2.f*(aLh[2]+aLl[2]+lp4.z));
      LG4.w = sigmf(aGh[3]+aGl[3]+gp4.w) * sigmf(2.f*(aLh[3]+aLl[3]+lp4.w));
      if (la == 0){
        *(float4*)&LGb[w*16 + g*4] = LG4;
        bf16x4 lgp;
        lgp[0]=(__bf16)LG4.x; lgp[1]=(__bf16)LG4.y;
        lgp[2]=(__bf16)LG4.z; lgp[3]=(__bf16)LG4.w;
        *(bf16x4*)&LGh[w*16 + g*4] = lgp;
      }
    }
    __syncthreads();                                    // Bb

    // ---- MAIN ----
    // prefetch issue + hist store (half 0 only; hidden under MFMA phase)
    float4 pf23, pf4, pfqe;
    const bool dopf = (tau < 126);
    const bool do23 = dopf && (tid < 64);
    const bool do4  = dopf && (tid >= 64) && (tid < 96);
    const bool doqe = dopf && (tid >= 448);
    if (do23) pf23 = *(const float4*)(pre23b + (tau+1)*256 + tid*4);
    if (do4)  pf4  = *(const float4*)(pre4b  + (tau+1)*128 + (tid-64)*4);
    if (doqe) pfqe = *(const float4*)(qmat + (size_t)qsl[tau+2]*256 + (tid-448)*4);
    if (half == 0 && tau > 0 && tid >= 96 && tid < 128){
      int i = (tid - 96)*4;
      float4 v0 = *(const float4*)&htc[i];
      float4 v1 = *(const float4*)&htc[128 + i];
      float4 v2 = *(const float4*)(xp + i);
      float4 v = {v0.x+v1.x+v2.x, v0.y+v1.y+v2.y, v0.z+v1.z+v2.z, v0.w+v1.w+v2.w};
      *(float4*)(hist + ((size_t)b*127 + (tau-1))*128 + i) = v;
    }

    // z = W4l @ LG + pre4, in-register (rows aligned with update k0)
    float4 z4[2];
    {
      bf16x8 lh[4];
      #pragma unroll
      for (int kt = 0; kt < 4; kt++)
        lh[kt] = *(const bf16x8*)&LGh[kt*32 + g*8];
      #pragma unroll
      for (int jj = 0; jj < 2; jj++){
        f32x4 az = {0.f,0.f,0.f,0.f};
        #pragma unroll
        for (int kt = 0; kt < 4; kt++)
          az = mfma16(af4l[jj][kt], lh[kt], az);
        float4 zp = *(const float4*)&p4c[(jq*2+jj)*16 + g*4];
        z4[jj].x = az[0]+zp.x; z4[jj].y = az[1]+zp.y;
        z4[jj].z = az[2]+zp.z; z4[jj].w = az[3]+zp.w;
      }
    }
    float4 lg4[2];
    #pragma unroll
    for (int jj = 0; jj < 2; jj++)
      lg4[jj] = *(const float4*)&LGb[(jq*2+jj)*16 + g*4];

    // software-pipelined bfv: load cg+1 while computing cg
    bf16x8 bA[4], bB[4];
    {
      const int base = rb[0] + roff;
      #pragma unroll
      for (int kt = 0; kt < 4; kt++) bA[kt] = *(const bf16x8*)&hB[base + kt*512];
    }
    f32x4 r0 = {0.f,0.f,0.f,0.f}, r1 = {0.f,0.f,0.f,0.f};
    #pragma unroll
    for (int cg = 0; cg < 4; cg++){
      const bf16x8* cur = (cg & 1) ? bB : bA;
      bf16x8*       nxt = (cg & 1) ? bA : bB;
      if (cg < 3){
        const int base = rb[cg+1] + roff;
        #pragma unroll
        for (int kt = 0; kt < 4; kt++) nxt[kt] = *(const bf16x8*)&hB[base + kt*512];
      }
      const int c_ = half*128 + ch*64 + cg*16 + la;
      const float qe_t = qec[c_], qe_n = qen[c_];
      const int wbase = wb[cg] + woff;
      #pragma unroll
      for (int jj = 0; jj < 2; jj++){
        f32x4 acc = {0.f,0.f,0.f,0.f};
        #pragma unroll
        for (int kt = 0; kt < 4; kt++)
          acc = mfma16(af[jj][kt], cur[kt], acc);
        float4 hp = hreg[cg][jj];
        float4 hn;
        hn.x = qe_t*lg4[jj].x + sigmf(acc[0] + z4[jj].x)*hp.x;
        hn.y = qe_t*lg4[jj].y + sigmf(acc[1] + z4[jj].y)*hp.y;
        hn.z = qe_t*lg4[jj].z + sigmf(acc[2] + z4[jj].z)*hp.z;
        hn.w = qe_t*lg4[jj].w + sigmf(acc[3] + z4[jj].w)*hp.w;
        hreg[cg][jj] = hn;
        bf16x4 hb; hb[0]=(__bf16)hn.x; hb[1]=(__bf16)hn.y; hb[2]=(__bf16)hn.z; hb[3]=(__bf16)hn.w;
        *(bf16x4*)&hB[wbase + jj*256] = hb;
        f32x4& r = (jj == 0) ? r0 : r1;
        r[0] += qe_n*hn.x; r[1] += qe_n*hn.y;
        r[2] += qe_n*hn.z; r[3] += qe_n*hn.w;
      }
    }
    // h_tilde local partial: DPP reduce + split plain stores
    red16(r0); red16(r1);
    if (la == 15){
      float4 s0 = {r0[0],r0[1],r0[2],r0[3]};
      float4 s1 = {r1[0],r1[1],r1[2],r1[3]};
      *(float4*)&htn[ch*128 + jq*32 + g*4]      = s0;
      *(float4*)&htn[ch*128 + jq*32 + 16 + g*4] = s1;
    }
    // prefetch writes (different buffers than those read this step)
    if (do23) *(float4*)&p23L[((tau+1)&1)*256 + tid*4] = pf23;
    if (do4)  *(float4*)&p4L[((tau+1)&1)*128 + (tid-64)*4] = pf4;
    if (doqe) *(float4*)&qep[(tid-448)*4] = pfqe;       // qe[tau+2]
    __syncthreads();                                    // B2
    int t_ = i0; i0 = i1; i1 = i2; i2 = t_;
  }

  // ---- epilogue: state 127 (htn of tau=126 lives in htb1) ----
  if (half == 1){
    // publish slot 127 for half 0
    if (w == 0){
      if (lane < 32){
        float4 v0 = *(const float4*)&htb1[lane*4];
        float4 v1 = *(const float4*)&htb1[128 + lane*4];
        float4 v = {v0.x+v1.x, v0.y+v1.y, v0.z+v1.z, v0.w+v1.w};
        *(float4*)(xmine + (size_t)127*128 + lane*4) = v;
      }
      __threadfence();
      if (lane == 0)
        __hip_atomic_store(&fmine[127], 1, __ATOMIC_RELEASE, __HIP_MEMORY_SCOPE_AGENT);
    }
  } else {
    if (tid < 32){
      int it = 0;
      while (__hip_atomic_load(&fpeer[127], __ATOMIC_ACQUIRE, __HIP_MEMORY_SCOPE_AGENT) == 0){
        __builtin_amdgcn_s_sleep(2);
        if (++it > (1 << 22)) break;
      }
      int i = tid*4;
      float4 v0 = *(const float4*)&htb1[i];
      float4 v1 = *(const float4*)&htb1[128 + i];
      float4 v2 = *(const float4*)(xpeer + (size_t)127*128 + i);
      float4 v = {v0.x+v1.x+v2.x, v0.y+v1.y+v2.y, v0.z+v1.z+v2.z, v0.w+v1.w+v2.w};
      *(float4*)(hist + ((size_t)b*127 + 126)*128 + i) = v;
    }
  }
}

// ---------------- K4: batched y ----------------
__global__ __launch_bounds__(128) void k4_y(
    const float* __restrict__ hist, const float* __restrict__ pre5,
    const float* __restrict__ W5, float* __restrict__ out)
{
  const int R = blockIdx.x;            // 0..4095 = b*128+s
  const int s = R & 127, b = R >> 7;
  const int j = threadIdx.x;
  __shared__ float xs[128];
  __shared__ float partial[2];
  if (s == 0){ if (j == 0) out[R] = 0.f; return; }
  xs[j] = hist[((size_t)b*127 + (s-1))*128 + j];
  __syncthreads();
  const float* wr = W5 + j*256 + 128;
  float acc = pre5[(size_t)R*128 + j];
  #pragma unroll
  for (int k = 0; k < 128; k += 4){
    float4 wv = *(const float4*)&wr[k];
    float4 xv = *(const float4*)&xs[k];
    acc += wv.x*xv.x + wv.y*xv.y + wv.z*xv.z + wv.w*xv.w;
  }
  float v = sigmf(acc);
  #pragma unroll
  for (int m = 1; m < 64; m <<= 1) v += __shfl_xor(v, m);
  if ((j & 63) == 0) partial[j >> 6] = v;
  __syncthreads();
  if (j == 0) out[R] = (partial[0] + partial[1]) * (1.f/128.f);
}

// ---------------- host launch ----------------
extern "C" void kernel_launch(void* const* d_in, const int* in_sizes, int n_in,
                              void* d_out, int out_size, void* d_ws, size_t ws_size,
                              hipStream_t stream) {
  const int*   qseq  = (const int*)  d_in[0];
  const int*   itseq = (const int*)  d_in[1];
  const int*   utseq = (const int*)  d_in[2];
  const float* corr  = (const float*)d_in[3];
  const float* Eq    = (const float*)d_in[4];
  const float* Eit   = (const float*)d_in[5];
  const float* Eut   = (const float*)d_in[6];
  const float* qmat  = (const float*)d_in[7];
  const float* h0    = (const float*)d_in[8];
  const float* W1    = (const float*)d_in[9];
  const float* b1    = (const float*)d_in[10];
  const float* W2    = (const float*)d_in[11];
  const float* b2    = (const float*)d_in[12];
  const float* W3    = (const float*)d_in[13];
  const float* b3    = (const float*)d_in[14];
  const float* W4    = (const float*)d_in[15];
  const float* b4    = (const float*)d_in[16];
  const float* W5    = (const float*)d_in[17];
  const float* b5    = (const float*)d_in[18];
  float* out = (float*)d_out;

  float* ws    = (float*)d_ws;
  float* AL    = ws;                    // 4096*128 ; reused as hist after k2
  float* hist  = ws;                    // 32*127*128 <= AL size
  float* pre5  = ws + 524288;           // 4096*128
  float* pre23 = ws + 1048576;          // 4064*256
  float* pre4  = ws + 2088960;          // 4064*128
  float* xbuf  = ws + 2609152;          // 64*128*128 = 1048576 f
  int*   flags = (int*)(ws + 3657728);  // 64*128 ints

  (void)hipFuncSetAttribute(reinterpret_cast<const void*>(&lpkt_scan),
                            hipFuncAttributeMaxDynamicSharedMemorySize,
                            SCAN_LDS_BYTES);

  hipMemsetAsync(flags, 0, 64*128*sizeof(int), stream);
  hipLaunchKernelGGL(k1_al, dim3(64), dim3(256), 0, stream,
                     qseq, utseq, corr, Eq, Eut, W1, b1, W5, b5, AL, pre5);
  hipLaunchKernelGGL(k2_pre, dim3(64), dim3(256), 0, stream,
                     itseq, Eit, AL, W2, W3, W4, b2, b3, b4, pre23, pre4);
  hipLaunchKernelGGL(lpkt_scan, dim3(64), dim3(512), SCAN_LDS_BYTES, stream,
                     qmat, qseq, h0, W2, W3, W4, pre23, pre4, hist, xbuf, flags);
  hipLaunchKernelGGL(k4_y, dim3(4096), dim3(128), 0, stream,
                     hist, pre5, W5, out);
}

// Round 9
// 1392.023 us; speedup vs baseline: 1.3232x; 1.3232x over previous
//
#include <hip/hip_runtime.h>
#include <hip/hip_bf16.h>

// LPKT+ forward. B=32, S=128, C=256, K=128, DC=128, T=127 scan steps.
//
//  K1: AL = [eq|eut]@W1a^T + b1 + correct*rs1c ; pre5 = eq@W5q^T + b5
//  K2: pre23 = [AL[t-1]|it|AL[t]] @ [W2a|W3a]^T + b ; pre4 = it@W4i^T + b4
//  K3 (scan): 32 blocks x 512 threads (8 waves = 2 j-halves x 4 col-quarters).
//      h fp32 in registers + bf16 shadow in LDS (dbuf, subtiled, conflict-
//      free). Wave owns 64 j-rows x 64 columns -> bfv read amplification 2x
//      (16 b128/lane). h_tilde single-buffer via la15 atomics + DPP reduce.
//      3 barriers/step. Epilogue computes y inline (k4 folded).

typedef __bf16 bf16x8 __attribute__((ext_vector_type(8)));
typedef __bf16 bf16x4 __attribute__((ext_vector_type(4)));
typedef float f32x4 __attribute__((ext_vector_type(4)));

#define HBUF 16384*2             // elems per h-shadow buffer (256x128 bf16)

__device__ __forceinline__ float sigmf(float x){
  return __builtin_amdgcn_rcpf(1.0f + __expf(-x));
}

__device__ __forceinline__ bf16x8 cvt8(float4 a, float4 b){
  bf16x8 r;
  r[0]=(__bf16)a.x; r[1]=(__bf16)a.y; r[2]=(__bf16)a.z; r[3]=(__bf16)a.w;
  r[4]=(__bf16)b.x; r[5]=(__bf16)b.y; r[6]=(__bf16)b.z; r[7]=(__bf16)b.w;
  return r;
}

// hi/lo bf16 split of 8 fp32 values (fp32-grade MFMA input)
__device__ __forceinline__ void mk_hilo(float4 a, float4 b, bf16x8& hi, bf16x8& lo){
  float v[8] = {a.x,a.y,a.z,a.w,b.x,b.y,b.z,b.w};
  #pragma unroll
  for (int i = 0; i < 8; i++){
    __bf16 h = (__bf16)v[i];
    hi[i] = h;
    lo[i] = (__bf16)(v[i] - (float)h);
  }
}

__device__ __forceinline__ f32x4 mfma16(bf16x8 a, bf16x8 b, f32x4 c){
  return __builtin_amdgcn_mfma_f32_16x16x32_bf16(a, b, c, 0, 0, 0);
}

// sum over each row of 16 lanes via DPP row_shr (VALU pipe, not LDS).
// Result valid in lane la==15 of each row.
__device__ __forceinline__ float dpp_sum16(float v){
  int x;
  x = __builtin_amdgcn_update_dpp(0, __builtin_bit_cast(int, v), 0x111, 0xf, 0xf, true);
  v += __builtin_bit_cast(float, x);
  x = __builtin_amdgcn_update_dpp(0, __builtin_bit_cast(int, v), 0x112, 0xf, 0xf, true);
  v += __builtin_bit_cast(float, x);
  x = __builtin_amdgcn_update_dpp(0, __builtin_bit_cast(int, v), 0x114, 0xf, 0xf, true);
  v += __builtin_bit_cast(float, x);
  x = __builtin_amdgcn_update_dpp(0, __builtin_bit_cast(int, v), 0x118, 0xf, 0xf, true);
  v += __builtin_bit_cast(float, x);
  return v;
}

__device__ __forceinline__ void red16(f32x4& r){
  r[0] = dpp_sum16(r[0]);
  r[1] = dpp_sum16(r[1]);
  r[2] = dpp_sum16(r[2]);
  r[3] = dpp_sum16(r[3]);
}

// ---------------- K1 ----------------
__global__ __launch_bounds__(256) void k1_al(
    const int* __restrict__ qseq, const int* __restrict__ utseq,
    const float* __restrict__ corr,
    const float* __restrict__ Eq, const float* __restrict__ Eut,
    const float* __restrict__ W1, const float* __restrict__ b1,
    const float* __restrict__ W5, const float* __restrict__ b5,
    float* __restrict__ AL, float* __restrict__ pre5)
{
  __shared__ __bf16 inA[64*256];
  __shared__ float corrs[64];
  __shared__ float b1s[128], b5s[128], rsp[256];
  const int tid = threadIdx.x, blk = blockIdx.x;
  if (tid < 128){ b1s[tid]=b1[tid]; b5s[tid]=b5[tid]; }
  { // rs1c partial sums
    int j = tid & 127, hf = tid >> 7;
    const float* p = W1 + j*384 + 256 + hf*64;
    float s = 0.f;
    for (int i = 0; i < 64; i++) s += p[i];
    rsp[tid] = s;
  }
  {
    int r = tid >> 2, seg = tid & 3;
    int R = blk*64 + r;
    int qi = qseq[R], ui = utseq[R];
    if (seg == 0) corrs[r] = corr[R];
    for (int i = 0; i < 64; i++){
      int col = seg*64 + i;
      float v = (col < 128) ? Eq[qi*128 + col] : Eut[ui*128 + (col-128)];
      inA[((r*256 + col) ^ ((r&7)<<3))] = (__bf16)v;
    }
  }
  __syncthreads();
  const int w = tid >> 6, lane = tid & 63;
  const int la = lane & 15, g = lane >> 4;
  const int rbase = w*16;
  bf16x8 af[8];
  #pragma unroll
  for (int kt = 0; kt < 8; kt++){
    int idx = ((rbase+la)*256 + kt*32 + g*8) ^ ((la&7)<<3);
    af[kt] = *(const bf16x8*)&inA[idx];
  }
  for (int jt = 0; jt < 8; jt++){
    f32x4 acc = {0.f,0.f,0.f,0.f};
    const float* Wb = W1 + (jt*16+la)*384;
    #pragma unroll
    for (int kt = 0; kt < 8; kt++){
      const float* p = Wb + kt*32 + g*8;
      acc = mfma16(af[kt], cvt8(*(const float4*)p, *(const float4*)(p+4)), acc);
    }
    int j = jt*16 + la;
    float rsj = rsp[j] + rsp[j+128];
    #pragma unroll
    for (int rr = 0; rr < 4; rr++){
      int row = rbase + g*4 + rr;
      int R = blk*64 + row;
      AL[R*128 + j] = acc[rr] + b1s[j] + corrs[row]*rsj;
    }
  }
  for (int jt = 0; jt < 8; jt++){
    f32x4 acc = {0.f,0.f,0.f,0.f};
    const float* Wb = W5 + (jt*16+la)*256;
    #pragma unroll
    for (int kt = 0; kt < 4; kt++){
      const float* p = Wb + kt*32 + g*8;
      acc = mfma16(af[kt], cvt8(*(const float4*)p, *(const float4*)(p+4)), acc);
    }
    int j = jt*16 + la;
    #pragma unroll
    for (int rr = 0; rr < 4; rr++){
      int row = rbase + g*4 + rr;
      int R = blk*64 + row;
      pre5[R*128 + j] = acc[rr] + b5s[j];
    }
  }
}

// ---------------- K2 ----------------
__global__ __launch_bounds__(256) void k2_pre(
    const int* __restrict__ itseq, const float* __restrict__ Eit,
    const float* __restrict__ AL,
    const float* __restrict__ W2, const float* __restrict__ W3,
    const float* __restrict__ W4,
    const float* __restrict__ b2, const float* __restrict__ b3,
    const float* __restrict__ b4,
    float* __restrict__ pre23, float* __restrict__ pre4)
{
  __shared__ __bf16 inA[64*384];
  __shared__ int obase[64];
  __shared__ float b2s[128], b3s[128], b4s[128];
  const int tid = threadIdx.x, blk = blockIdx.x;
  if (tid < 128){ b2s[tid]=b2[tid]; b3s[tid]=b3[tid]; b4s[tid]=b4[tid]; }
  {
    int r = tid >> 2, seg = tid & 3;
    int R = blk*64 + r;
    bool valid = (R < 4064);
    int b_ = R / 127, tau = R % 127;
    if (seg == 0) obase[r] = valid ? (b_*127 + tau) : -1;
    int itv = valid ? itseq[b_*128 + tau] : 0;
    for (int i = 0; i < 96; i++){
      int col = seg*96 + i;
      float v = 0.f;
      if (valid){
        if (col < 128)      v = (tau > 0) ? AL[(b_*128 + tau-1)*128 + col] : 0.f;
        else if (col < 256) v = Eit[itv*128 + (col-128)];
        else                v = AL[(b_*128 + tau)*128 + (col-256)];
      }
      inA[((r*384 + col) ^ ((r&7)<<3))] = (__bf16)v;
    }
  }
  __syncthreads();
  const int w = tid >> 6, lane = tid & 63;
  const int la = lane & 15, g = lane >> 4;
  const int rbase = w*16;
  bf16x8 af[12];
  #pragma unroll
  for (int kt = 0; kt < 12; kt++){
    int idx = ((rbase+la)*384 + kt*32 + g*8) ^ ((la&7)<<3);
    af[kt] = *(const bf16x8*)&inA[idx];
  }
  for (int jt = 0; jt < 16; jt++){
    f32x4 acc = {0.f,0.f,0.f,0.f};
    int j = jt*16 + la;
    const float* Wb = (j < 128) ? (W2 + j*512) : (W3 + (j-128)*512);
    #pragma unroll
    for (int kt = 0; kt < 12; kt++){
      const float* p = Wb + kt*32 + g*8;
      acc = mfma16(af[kt], cvt8(*(const float4*)p, *(const float4*)(p+4)), acc);
    }
    float bias = (j < 128) ? b2s[j] : b3s[j-128];
    #pragma unroll
    for (int rr = 0; rr < 4; rr++){
      int row = rbase + g*4 + rr;
      int ob = obase[row];
      if (ob >= 0) pre23[ob*256 + j] = acc[rr] + bias;
    }
  }
  for (int jt = 0; jt < 8; jt++){
    f32x4 acc = {0.f,0.f,0.f,0.f};
    int j = jt*16 + la;
    const float* Wb = W4 + j*384 + 256;
    #pragma unroll
    for (int kk = 0; kk < 4; kk++){
      const float* p = Wb + kk*32 + g*8;
      acc = mfma16(af[4+kk], cvt8(*(const float4*)p, *(const float4*)(p+4)), acc);
    }
    #pragma unroll
    for (int rr = 0; rr < 4; rr++){
      int row = rbase + g*4 + rr;
      int ob = obase[row];
      if (ob >= 0) pre4[ob*128 + j] = acc[rr] + b4s[j];
    }
  }
}

// ---------------- K3: scan, 32 blocks x 512 threads ----------------
// LDS floats: hB bf16 2x32768 = 32768 f | htb0 128 | htb1 128 | LGb 128 |
//   zb 128 | LGh(bf16) 64 | qeb[3][256] 768 | p23L[2][256] 512 |
//   p4L[2][128] 256 | qsl(int) 128  => 35008 f = 140032 B
#define SCAN_LDS_BYTES (35008*4)

__global__ __launch_bounds__(512, 2) void lpkt_scan(
    const float* __restrict__ qmat, const int* __restrict__ qseq,
    const float* __restrict__ h0,
    const float* __restrict__ W2, const float* __restrict__ W3,
    const float* __restrict__ W4, const float* __restrict__ W5,
    const float* __restrict__ pre23, const float* __restrict__ pre4,
    const float* __restrict__ pre5,
    float* __restrict__ hist, float* __restrict__ out)
{
  extern __shared__ float lds[];
  __bf16* hB   = (__bf16*)lds;            // 2 x subtiled 256x128
  float*  htb0 = lds + 32768;             // [128]
  float*  htb1 = lds + 32896;             // [128]
  float*  LGb  = lds + 33024;             // fp32 LG
  float*  zb   = lds + 33152;             // fp32 z
  __bf16* LGh  = (__bf16*)(lds + 33280);  // bf16 LG
  float*  qeb  = lds + 33344;             // [3][256]
  float*  p23L = lds + 34112;             // [2][256]
  float*  p4L  = lds + 34624;             // [2][128]
  int*    qsl  = (int*)(lds + 34880);

  const int tid  = threadIdx.x;
  const int b    = blockIdx.x;
  const int lane = tid & 63;
  const int w    = tid >> 6;           // 8 waves
  const int la   = lane & 15, g = lane >> 4;
  const int jh   = w & 1;              // j-half (64 k-rows)
  const int cq   = w >> 1;             // column quarter (64 columns)

  // ---- persistent register weight fragments (MFMA-A -> AGPR-friendly) ----
  bf16x8 af[4][4];                     // W4h rows (jh*4+jj)*16+la
  #pragma unroll
  for (int jj = 0; jj < 4; jj++){
    #pragma unroll
    for (int kt = 0; kt < 4; kt++){
      const float* ph = W4 + ((jh*4+jj)*16+la)*384 + kt*32 + g*8;
      af[jj][kt] = cvt8(*(const float4*)ph, *(const float4*)(ph+4));
    }
  }
  bf16x8 af4l[4];                      // W4l rows w*16+la (z tile w)
  bf16x8 af23[2][4];                   // W2h tile w, W3h tile w
  #pragma unroll
  for (int kt = 0; kt < 4; kt++){
    const float* pl = W4 + (w*16+la)*384 + 128 + kt*32 + g*8;
    const float* p2 = W2 + (w*16+la)*512 + 384 + kt*32 + g*8;
    const float* p3 = W3 + (w*16+la)*512 + 384 + kt*32 + g*8;
    af4l[kt]    = cvt8(*(const float4*)pl, *(const float4*)(pl+4));
    af23[0][kt] = cvt8(*(const float4*)p2, *(const float4*)(p2+4));
    af23[1][kt] = cvt8(*(const float4*)p3, *(const float4*)(p3+4));
  }

  // ---- precomputed LDS bases (buffer 0; parity adds HBUF) ----
  // subtiled: elem(c,k) -> ((c>>4)*16 + (k>>3))*128 + (c&15)*8 + (k&7)
  int rb[4], wb[4];
  #pragma unroll
  for (int cg = 0; cg < 4; cg++){
    const int cblk = cq*4 + cg;          // c>>4 for c = cq*64+cg*16+la
    rb[cg] = cblk*2048 + g*128 + la*8;                            // + kt*512
    wb[cg] = cblk*2048 + jh*1024 + (g>>1)*128 + la*8 + (g&1)*4;   // + jj*256
  }

  // ---- init staging ----
  if (tid < 128) qsl[tid] = qseq[b*128 + tid];
  __syncthreads();
  const float* pre23b = pre23 + b*127*256;
  const float* pre4b  = pre4  + b*127*128;
  if (tid < 64)       *(float4*)&qeb[tid*4] = *(const float4*)(qmat + (size_t)qsl[0]*256 + tid*4);
  else if (tid < 128) *(float4*)&qeb[256 + (tid-64)*4] = *(const float4*)(qmat + (size_t)qsl[1]*256 + (tid-64)*4);
  else if (tid < 192) *(float4*)&p23L[(tid-128)*4] = *(const float4*)(pre23b + (tid-128)*4);
  else if (tid < 224) *(float4*)&p4L[(tid-192)*4]  = *(const float4*)(pre4b  + (tid-192)*4);
  else if (tid < 256){ float4 z4i = {0.f,0.f,0.f,0.f}; *(float4*)&htb0[(tid-224)*4] = z4i; }

  // h state -> registers (fp32, D-layout) + bf16 shadow buffer 0
  float4 hreg[4][4];
  #pragma unroll
  for (int cg = 0; cg < 4; cg++){
    const int c_ = cq*64 + cg*16 + la;
    #pragma unroll
    for (int jj = 0; jj < 4; jj++){
      const int k0 = (jh*4+jj)*16 + g*4;
      float4 v = *(const float4*)(h0 + c_*128 + k0);
      hreg[cg][jj] = v;
      bf16x4 hb; hb[0]=(__bf16)v.x; hb[1]=(__bf16)v.y; hb[2]=(__bf16)v.z; hb[3]=(__bf16)v.w;
      *(bf16x4*)&hB[wb[cg] + jj*256] = hb;
    }
  }
  __syncthreads();
  // htilde0 partials (DPP reduce + la15 atomics into zeroed htb0)
  {
    f32x4 r[4] = {{0.f,0.f,0.f,0.f},{0.f,0.f,0.f,0.f},
                  {0.f,0.f,0.f,0.f},{0.f,0.f,0.f,0.f}};
    #pragma unroll
    for (int cg = 0; cg < 4; cg++){
      const int c_ = cq*64 + cg*16 + la;
      float q = qeb[c_];
      #pragma unroll
      for (int jj = 0; jj < 4; jj++){
        float4 hv = hreg[cg][jj];
        r[jj][0] += q*hv.x; r[jj][1] += q*hv.y;
        r[jj][2] += q*hv.z; r[jj][3] += q*hv.w;
      }
    }
    #pragma unroll
    for (int jj = 0; jj < 4; jj++) red16(r[jj]);
    if (la == 15){
      #pragma unroll
      for (int jj = 0; jj < 4; jj++){
        const int k0 = (jh*4+jj)*16 + g*4;
        atomicAdd(&htb0[k0+0], r[jj][0]); atomicAdd(&htb0[k0+1], r[jj][1]);
        atomicAdd(&htb0[k0+2], r[jj][2]); atomicAdd(&htb0[k0+3], r[jj][3]);
      }
    }
  }
  __syncthreads();

  int i0 = 0, i1 = 1, i2 = 2;          // qe triple-buffer rotation

  for (int tau = 0; tau < 127; tau++){
    float* htc = (tau & 1) ? htb1 : htb0;       // [128] complete h_tilde
    float* htn = (tau & 1) ? htb0 : htb1;
    float* qec = qeb + i0*256;
    float* qen = qeb + i1*256;
    float* qep = qeb + i2*256;
    const float* p23c = p23L + (tau & 1)*256;
    const float* p4c  = p4L  + (tau & 1)*128;
    const int roff = (tau & 1) ? HBUF : 0;
    const int woff = (tau & 1) ? 0 : HBUF;

    // ---- P0: zero htn; m23 via MFMA (hi/lo); LG on all lanes ----
    if (tid < 128) htn[tid] = 0.f;
    {
      bf16x8 xh[4], xl[4];
      #pragma unroll
      for (int kt = 0; kt < 4; kt++){
        int k0 = kt*32 + g*8;
        mk_hilo(*(const float4*)&htc[k0], *(const float4*)&htc[k0+4], xh[kt], xl[kt]);
      }
      f32x4 aLh = {0.f,0.f,0.f,0.f}, aLl = {0.f,0.f,0.f,0.f};
      f32x4 aGh = {0.f,0.f,0.f,0.f}, aGl = {0.f,0.f,0.f,0.f};
      #pragma unroll
      for (int kt = 0; kt < 4; kt++){
        aLh = mfma16(af23[0][kt], xh[kt], aLh);
        aLl = mfma16(af23[0][kt], xl[kt], aLl);
        aGh = mfma16(af23[1][kt], xh[kt], aGh);
        aGl = mfma16(af23[1][kt], xl[kt], aGl);
      }
      float4 lp4 = *(const float4*)&p23c[w*16 + g*4];
      float4 gp4 = *(const float4*)&p23c[128 + w*16 + g*4];
      float4 LG4;
      LG4.x = sigmf(aGh[0]+aGl[0]+gp4.x) * sigmf(2.f*(aLh[0]+aLl[0]+lp4.x));
      LG4.y = sigmf(aGh[1]+aGl[1]+gp4.y) * sigmf(2.f*(aLh[1]+aLl[1]+lp4.y));
      LG4.z = sigmf(aGh[2]+aGl[2]+gp4.z) * sigmf(2.f*(aLh[2]+aLl[2]+lp4.z));
      LG4.w = sigmf(aGh[3]+aGl[3]+gp4.w) * sigmf(2.f*(aLh[3]+aLl[3]+lp4.w));
      if (la == 0){
        *(float4*)&LGb[w*16 + g*4] = LG4;
        bf16x4 lgp;
        lgp[0]=(__bf16)LG4.x; lgp[1]=(__bf16)LG4.y;
        lgp[2]=(__bf16)LG4.z; lgp[3]=(__bf16)LG4.w;
        *(bf16x4*)&LGh[w*16 + g*4] = lgp;
      }
    }
    __syncthreads();                                    // Bb

    // ---- P1: z tile w = W4l @ LG + pre4 (shared via zb) ----
    {
      bf16x8 lh[4];
      #pragma unroll
      for (int kt = 0; kt < 4; kt++)
        lh[kt] = *(const bf16x8*)&LGh[kt*32 + g*8];
      f32x4 az0 = {0.f,0.f,0.f,0.f}, az1 = {0.f,0.f,0.f,0.f};
      az0 = mfma16(af4l[0], lh[0], az0);
      az1 = mfma16(af4l[1], lh[1], az1);
      az0 = mfma16(af4l[2], lh[2], az0);
      az1 = mfma16(af4l[3], lh[3], az1);
      if (la == 0){
        float4 zp = *(const float4*)&p4c[w*16 + g*4];
        float4 zv = {az0[0]+az1[0]+zp.x, az0[1]+az1[1]+zp.y,
                     az0[2]+az1[2]+zp.z, az0[3]+az1[3]+zp.w};
        *(float4*)&zb[w*16 + g*4] = zv;
      }
    }
    __syncthreads();                                    // B1

    // ---- MAIN ----
    // prefetch issue + hist store (hidden under MFMA phase)
    float4 pf23, pf4, pfqe;
    const bool dopf = (tau < 126);
    const bool do23 = dopf && (tid < 64);
    const bool do4  = dopf && (tid >= 64) && (tid < 96);
    const bool doqe = dopf && (tid >= 448);
    if (do23) pf23 = *(const float4*)(pre23b + (tau+1)*256 + tid*4);
    if (do4)  pf4  = *(const float4*)(pre4b  + (tau+1)*128 + (tid-64)*4);
    if (doqe) pfqe = *(const float4*)(qmat + (size_t)qsl[tau+2]*256 + (tid-448)*4);
    if (tau > 0 && tid >= 96 && tid < 128){
      int i = (tid - 96)*4;
      *(float4*)(hist + ((size_t)b*127 + (tau-1))*128 + i) = *(const float4*)&htc[i];
    }

    // hoisted per-jj z/LG (cg-invariant)
    float4 z4[4], lg4[4];
    #pragma unroll
    for (int jj = 0; jj < 4; jj++){
      const int k0 = (jh*4+jj)*16 + g*4;
      z4[jj]  = *(const float4*)&zb[k0];
      lg4[jj] = *(const float4*)&LGb[k0];
    }

    // software-pipelined bfv: load cg+1 while computing cg
    bf16x8 bA[4], bB[4];
    {
      const int base = rb[0] + roff;
      #pragma unroll
      for (int kt = 0; kt < 4; kt++) bA[kt] = *(const bf16x8*)&hB[base + kt*512];
    }
    f32x4 r[4] = {{0.f,0.f,0.f,0.f},{0.f,0.f,0.f,0.f},
                  {0.f,0.f,0.f,0.f},{0.f,0.f,0.f,0.f}};
    #pragma unroll
    for (int cg = 0; cg < 4; cg++){
      const bf16x8* cur = (cg & 1) ? bB : bA;
      bf16x8*       nxt = (cg & 1) ? bA : bB;
      if (cg < 3){
        const int base = rb[cg+1] + roff;
        #pragma unroll
        for (int kt = 0; kt < 4; kt++) nxt[kt] = *(const bf16x8*)&hB[base + kt*512];
      }
      const int c_ = cq*64 + cg*16 + la;
      const float qe_t = qec[c_], qe_n = qen[c_];
      const int wbase = wb[cg] + woff;
      #pragma unroll
      for (int jj = 0; jj < 4; jj++){
        f32x4 acc = {0.f,0.f,0.f,0.f};
        #pragma unroll
        for (int kt = 0; kt < 4; kt++)
          acc = mfma16(af[jj][kt], cur[kt], acc);
        float4 hp = hreg[cg][jj];
        float4 hn;
        hn.x = qe_t*lg4[jj].x + sigmf(acc[0] + z4[jj].x)*hp.x;
        hn.y = qe_t*lg4[jj].y + sigmf(acc[1] + z4[jj].y)*hp.y;
        hn.z = qe_t*lg4[jj].z + sigmf(acc[2] + z4[jj].z)*hp.z;
        hn.w = qe_t*lg4[jj].w + sigmf(acc[3] + z4[jj].w)*hp.w;
        hreg[cg][jj] = hn;
        bf16x4 hb; hb[0]=(__bf16)hn.x; hb[1]=(__bf16)hn.y; hb[2]=(__bf16)hn.z; hb[3]=(__bf16)hn.w;
        *(bf16x4*)&hB[wbase + jj*256] = hb;
        r[jj][0] += qe_n*hn.x; r[jj][1] += qe_n*hn.y;
        r[jj][2] += qe_n*hn.z; r[jj][3] += qe_n*hn.w;
      }
    }
    // h_tilde: DPP reduce + la15 atomics into zeroed htn
    #pragma unroll
    for (int jj = 0; jj < 4; jj++) red16(r[jj]);
    if (la == 15){
      #pragma unroll
      for (int jj = 0; jj < 4; jj++){
        const int k0 = (jh*4+jj)*16 + g*4;
        atomicAdd(&htn[k0+0], r[jj][0]); atomicAdd(&htn[k0+1], r[jj][1]);
        atomicAdd(&htn[k0+2], r[jj][2]); atomicAdd(&htn[k0+3], r[jj][3]);
      }
    }
    // prefetch writes (different buffers than those read this step)
    if (do23) *(float4*)&p23L[((tau+1)&1)*256 + tid*4] = pf23;
    if (do4)  *(float4*)&p4L[((tau+1)&1)*128 + (tid-64)*4] = pf4;
    if (doqe) *(float4*)&qep[(tid-448)*4] = pfqe;       // qe[tau+2]
    __syncthreads();                                    // B2
    int t_ = i0; i0 = i1; i1 = i2; i2 = t_;
  }

  // ---- epilogue: final h_tilde row, then y for all s (k4 folded) ----
  if (tid < 32){
    int i = tid*4;
    *(float4*)(hist + ((size_t)b*127 + 126)*128 + i) = *(const float4*)&htb1[i];
  }
  __syncthreads();
  {
    const int j = tid & 127, so = tid >> 7;       // 4 s per chunk
    float* ypart = lds;                           // reuse hB region [8]
    const float* wrow = W5 + j*256 + 128;
    for (int sc = 0; sc < 128; sc += 4){
      int s = sc + so;
      float acc = 0.f;
      if (s > 0){
        const float* xr = hist + ((size_t)b*127 + (s-1))*128;
        acc = pre5[(size_t)(b*128 + s)*128 + j];
        #pragma unroll
        for (int k = 0; k < 128; k += 4){
          float4 wv = *(const float4*)&wrow[k];
          float4 xv = *(const float4*)&xr[k];
          acc += wv.x*xv.x + wv.y*xv.y + wv.z*xv.z + wv.w*xv.w;
        }
        acc = sigmf(acc);
      }
      #pragma unroll
      for (int m = 1; m < 64; m <<= 1) acc += __shfl_xor(acc, m);
      if (lane == 0) ypart[w] = acc;              // w = so*2 + (j>>6)
      __syncthreads();
      if (tid < 4){
        int s2 = sc + tid;
        out[b*128 + s2] = (s2 == 0) ? 0.f
                        : (ypart[tid*2] + ypart[tid*2+1]) * (1.f/128.f);
      }
      __syncthreads();
    }
  }
}

// ---------------- host launch ----------------
extern "C" void kernel_launch(void* const* d_in, const int* in_sizes, int n_in,
                              void* d_out, int out_size, void* d_ws, size_t ws_size,
                              hipStream_t stream) {
  const int*   qseq  = (const int*)  d_in[0];
  const int*   itseq = (const int*)  d_in[1];
  const int*   utseq = (const int*)  d_in[2];
  const float* corr  = (const float*)d_in[3];
  const float* Eq    = (const float*)d_in[4];
  const float* Eit   = (const float*)d_in[5];
  const float* Eut   = (const float*)d_in[6];
  const float* qmat  = (const float*)d_in[7];
  const float* h0    = (const float*)d_in[8];
  const float* W1    = (const float*)d_in[9];
  const float* b1    = (const float*)d_in[10];
  const float* W2    = (const float*)d_in[11];
  const float* b2    = (const float*)d_in[12];
  const float* W3    = (const float*)d_in[13];
  const float* b3    = (const float*)d_in[14];
  const float* W4    = (const float*)d_in[15];
  const float* b4    = (const float*)d_in[16];
  const float* W5    = (const float*)d_in[17];
  const float* b5    = (const float*)d_in[18];
  float* out = (float*)d_out;

  float* ws    = (float*)d_ws;
  float* AL    = ws;                    // 4096*128 ; reused as hist after k2
  float* hist  = ws;                    // 32*127*128 <= AL size
  float* pre5  = ws + 524288;           // 4096*128
  float* pre23 = ws + 1048576;          // 4064*256
  float* pre4  = ws + 2088960;          // 4064*128

  (void)hipFuncSetAttribute(reinterpret_cast<const void*>(&lpkt_scan),
                            hipFuncAttributeMaxDynamicSharedMemorySize,
                            SCAN_LDS_BYTES);

  hipLaunchKernelGGL(k1_al, dim3(64), dim3(256), 0, stream,
                     qseq, utseq, corr, Eq, Eut, W1, b1, W5, b5, AL, pre5);
  hipLaunchKernelGGL(k2_pre, dim3(64), dim3(256), 0, stream,
                     itseq, Eit, AL, W2, W3, W4, b2, b3, b4, pre23, pre4);
  hipLaunchKernelGGL(lpkt_scan, dim3(32), dim3(512), SCAN_LDS_BYTES, stream,
                     qmat, qseq, h0, W2, W3, W4, W5, pre23, pre4, pre5,
                     hist, out);
}

// Round 10
// 1087.627 us; speedup vs baseline: 1.6935x; 1.2799x over previous
//
#include <hip/hip_runtime.h>
#include <hip/hip_bf16.h>

// LPKT+ forward. B=32, S=128, C=256, K=128, DC=128, T=127 scan steps.
//
//  K1: AL = [eq|eut]@W1a^T + b1 + correct*rs1c ; pre5 = eq@W5q^T + b5
//  K2: pre23 = [AL[t-1]|it|AL[t]] @ [W2a|W3a]^T + b ; pre4 = it@W4i^T + b4
//  K3 (scan): 32 blocks x 512 threads (8 waves = 4 j-quarters x 2 col-halves)
//      — the round-7 structure (spill-free at 160 persistent regs).
//      h fp32 in registers + bf16 shadow in LDS (dbuf, subtiled [c/16][k/8]
//      [c%16][8], conflict-free, base+imm addressing). z in-register in MAIN.
//      h_tilde via DPP reduce + split plain stores. 2 barriers/step.
//      Epilogue computes y inline (k4 folded — saves a launch).

typedef __bf16 bf16x8 __attribute__((ext_vector_type(8)));
typedef __bf16 bf16x4 __attribute__((ext_vector_type(4)));
typedef float f32x4 __attribute__((ext_vector_type(4)));

#define HBUF 32768               // elems per h-shadow buffer (256x128 bf16)

__device__ __forceinline__ float sigmf(float x){
  return __builtin_amdgcn_rcpf(1.0f + __expf(-x));
}

__device__ __forceinline__ bf16x8 cvt8(float4 a, float4 b){
  bf16x8 r;
  r[0]=(__bf16)a.x; r[1]=(__bf16)a.y; r[2]=(__bf16)a.z; r[3]=(__bf16)a.w;
  r[4]=(__bf16)b.x; r[5]=(__bf16)b.y; r[6]=(__bf16)b.z; r[7]=(__bf16)b.w;
  return r;
}

// hi/lo bf16 split of 8 fp32 values (fp32-grade MFMA input)
__device__ __forceinline__ void mk_hilo(float4 a, float4 b, bf16x8& hi, bf16x8& lo){
  float v[8] = {a.x,a.y,a.z,a.w,b.x,b.y,b.z,b.w};
  #pragma unroll
  for (int i = 0; i < 8; i++){
    __bf16 h = (__bf16)v[i];
    hi[i] = h;
    lo[i] = (__bf16)(v[i] - (float)h);
  }
}

__device__ __forceinline__ f32x4 mfma16(bf16x8 a, bf16x8 b, f32x4 c){
  return __builtin_amdgcn_mfma_f32_16x16x32_bf16(a, b, c, 0, 0, 0);
}

// sum over each row of 16 lanes via DPP row_shr (VALU pipe, not LDS).
// Result valid in lane la==15 of each row.
__device__ __forceinline__ float dpp_sum16(float v){
  int x;
  x = __builtin_amdgcn_update_dpp(0, __builtin_bit_cast(int, v), 0x111, 0xf, 0xf, true);
  v += __builtin_bit_cast(float, x);
  x = __builtin_amdgcn_update_dpp(0, __builtin_bit_cast(int, v), 0x112, 0xf, 0xf, true);
  v += __builtin_bit_cast(float, x);
  x = __builtin_amdgcn_update_dpp(0, __builtin_bit_cast(int, v), 0x114, 0xf, 0xf, true);
  v += __builtin_bit_cast(float, x);
  x = __builtin_amdgcn_update_dpp(0, __builtin_bit_cast(int, v), 0x118, 0xf, 0xf, true);
  v += __builtin_bit_cast(float, x);
  return v;
}

__device__ __forceinline__ void red16(f32x4& r){
  r[0] = dpp_sum16(r[0]);
  r[1] = dpp_sum16(r[1]);
  r[2] = dpp_sum16(r[2]);
  r[3] = dpp_sum16(r[3]);
}

// ---------------- K1 ----------------
__global__ __launch_bounds__(256) void k1_al(
    const int* __restrict__ qseq, const int* __restrict__ utseq,
    const float* __restrict__ corr,
    const float* __restrict__ Eq, const float* __restrict__ Eut,
    const float* __restrict__ W1, const float* __restrict__ b1,
    const float* __restrict__ W5, const float* __restrict__ b5,
    float* __restrict__ AL, float* __restrict__ pre5)
{
  __shared__ __bf16 inA[64*256];
  __shared__ float corrs[64];
  __shared__ float b1s[128], b5s[128], rsp[256];
  const int tid = threadIdx.x, blk = blockIdx.x;
  if (tid < 128){ b1s[tid]=b1[tid]; b5s[tid]=b5[tid]; }
  { // rs1c partial sums
    int j = tid & 127, hf = tid >> 7;
    const float* p = W1 + j*384 + 256 + hf*64;
    float s = 0.f;
    for (int i = 0; i < 64; i++) s += p[i];
    rsp[tid] = s;
  }
  {
    int r = tid >> 2, seg = tid & 3;
    int R = blk*64 + r;
    int qi = qseq[R], ui = utseq[R];
    if (seg == 0) corrs[r] = corr[R];
    for (int i = 0; i < 64; i++){
      int col = seg*64 + i;
      float v = (col < 128) ? Eq[qi*128 + col] : Eut[ui*128 + (col-128)];
      inA[((r*256 + col) ^ ((r&7)<<3))] = (__bf16)v;
    }
  }
  __syncthreads();
  const int w = tid >> 6, lane = tid & 63;
  const int la = lane & 15, g = lane >> 4;
  const int rbase = w*16;
  bf16x8 af[8];
  #pragma unroll
  for (int kt = 0; kt < 8; kt++){
    int idx = ((rbase+la)*256 + kt*32 + g*8) ^ ((la&7)<<3);
    af[kt] = *(const bf16x8*)&inA[idx];
  }
  for (int jt = 0; jt < 8; jt++){
    f32x4 acc = {0.f,0.f,0.f,0.f};
    const float* Wb = W1 + (jt*16+la)*384;
    #pragma unroll
    for (int kt = 0; kt < 8; kt++){
      const float* p = Wb + kt*32 + g*8;
      acc = mfma16(af[kt], cvt8(*(const float4*)p, *(const float4*)(p+4)), acc);
    }
    int j = jt*16 + la;
    float rsj = rsp[j] + rsp[j+128];
    #pragma unroll
    for (int rr = 0; rr < 4; rr++){
      int row = rbase + g*4 + rr;
      int R = blk*64 + row;
      AL[R*128 + j] = acc[rr] + b1s[j] + corrs[row]*rsj;
    }
  }
  for (int jt = 0; jt < 8; jt++){
    f32x4 acc = {0.f,0.f,0.f,0.f};
    const float* Wb = W5 + (jt*16+la)*256;
    #pragma unroll
    for (int kt = 0; kt < 4; kt++){
      const float* p = Wb + kt*32 + g*8;
      acc = mfma16(af[kt], cvt8(*(const float4*)p, *(const float4*)(p+4)), acc);
    }
    int j = jt*16 + la;
    #pragma unroll
    for (int rr = 0; rr < 4; rr++){
      int row = rbase + g*4 + rr;
      int R = blk*64 + row;
      pre5[R*128 + j] = acc[rr] + b5s[j];
    }
  }
}

// ---------------- K2 ----------------
__global__ __launch_bounds__(256) void k2_pre(
    const int* __restrict__ itseq, const float* __restrict__ Eit,
    const float* __restrict__ AL,
    const float* __restrict__ W2, const float* __restrict__ W3,
    const float* __restrict__ W4,
    const float* __restrict__ b2, const float* __restrict__ b3,
    const float* __restrict__ b4,
    float* __restrict__ pre23, float* __restrict__ pre4)
{
  __shared__ __bf16 inA[64*384];
  __shared__ int obase[64];
  __shared__ float b2s[128], b3s[128], b4s[128];
  const int tid = threadIdx.x, blk = blockIdx.x;
  if (tid < 128){ b2s[tid]=b2[tid]; b3s[tid]=b3[tid]; b4s[tid]=b4[tid]; }
  {
    int r = tid >> 2, seg = tid & 3;
    int R = blk*64 + r;
    bool valid = (R < 4064);
    int b_ = R / 127, tau = R % 127;
    if (seg == 0) obase[r] = valid ? (b_*127 + tau) : -1;
    int itv = valid ? itseq[b_*128 + tau] : 0;
    for (int i = 0; i < 96; i++){
      int col = seg*96 + i;
      float v = 0.f;
      if (valid){
        if (col < 128)      v = (tau > 0) ? AL[(b_*128 + tau-1)*128 + col] : 0.f;
        else if (col < 256) v = Eit[itv*128 + (col-128)];
        else                v = AL[(b_*128 + tau)*128 + (col-256)];
      }
      inA[((r*384 + col) ^ ((r&7)<<3))] = (__bf16)v;
    }
  }
  __syncthreads();
  const int w = tid >> 6, lane = tid & 63;
  const int la = lane & 15, g = lane >> 4;
  const int rbase = w*16;
  bf16x8 af[12];
  #pragma unroll
  for (int kt = 0; kt < 12; kt++){
    int idx = ((rbase+la)*384 + kt*32 + g*8) ^ ((la&7)<<3);
    af[kt] = *(const bf16x8*)&inA[idx];
  }
  for (int jt = 0; jt < 16; jt++){
    f32x4 acc = {0.f,0.f,0.f,0.f};
    int j = jt*16 + la;
    const float* Wb = (j < 128) ? (W2 + j*512) : (W3 + (j-128)*512);
    #pragma unroll
    for (int kt = 0; kt < 12; kt++){
      const float* p = Wb + kt*32 + g*8;
      acc = mfma16(af[kt], cvt8(*(const float4*)p, *(const float4*)(p+4)), acc);
    }
    float bias = (j < 128) ? b2s[j] : b3s[j-128];
    #pragma unroll
    for (int rr = 0; rr < 4; rr++){
      int row = rbase + g*4 + rr;
      int ob = obase[row];
      if (ob >= 0) pre23[ob*256 + j] = acc[rr] + bias;
    }
  }
  for (int jt = 0; jt < 8; jt++){
    f32x4 acc = {0.f,0.f,0.f,0.f};
    int j = jt*16 + la;
    const float* Wb = W4 + j*384 + 256;
    #pragma unroll
    for (int kk = 0; kk < 4; kk++){
      const float* p = Wb + kk*32 + g*8;
      acc = mfma16(af[4+kk], cvt8(*(const float4*)p, *(const float4*)(p+4)), acc);
    }
    #pragma unroll
    for (int rr = 0; rr < 4; rr++){
      int row = rbase + g*4 + rr;
      int ob = obase[row];
      if (ob >= 0) pre4[ob*128 + j] = acc[rr] + b4s[j];
    }
  }
}

// ---------------- K3: scan, 32 blocks x 512 threads ----------------
// LDS floats: hB bf16 2x32768 = 32768 f | htb0[2][128] 256 | htb1[2][128] 256 |
//   LGb 128 | LGh(bf16) 64 | qeb[3][256] 768 | p23L[2][256] 512 |
//   p4L[2][128] 256 | qsl(int) 128 => 35136 f = 140544 B
#define SCAN_LDS_BYTES (35136*4)

__global__ __launch_bounds__(512, 2) void lpkt_scan(
    const float* __restrict__ qmat, const int* __restrict__ qseq,
    const float* __restrict__ h0,
    const float* __restrict__ W2, const float* __restrict__ W3,
    const float* __restrict__ W4, const float* __restrict__ W5,
    const float* __restrict__ pre23, const float* __restrict__ pre4,
    const float* __restrict__ pre5,
    float* __restrict__ hist, float* __restrict__ out)
{
  extern __shared__ float lds[];
  __bf16* hB   = (__bf16*)lds;            // 2 x subtiled 256x128
  float*  htb0 = lds + 32768;             // [2][128]
  float*  htb1 = lds + 33024;             // [2][128]
  float*  LGb  = lds + 33280;             // fp32 LG
  __bf16* LGh  = (__bf16*)(lds + 33408);  // bf16 LG
  float*  qeb  = lds + 33472;             // [3][256]
  float*  p23L = lds + 34240;             // [2][256]
  float*  p4L  = lds + 34752;             // [2][128]
  int*    qsl  = (int*)(lds + 35008);

  const int tid  = threadIdx.x;
  const int b    = blockIdx.x;
  const int lane = tid & 63;
  const int w    = tid >> 6;           // 8 waves
  const int la   = lane & 15, g = lane >> 4;
  const int jq   = w & 3;              // j-quarter of k-dim outputs
  const int ch   = w >> 2;             // column half (128 columns)

  // ---- persistent register weight fragments (MFMA-A -> AGPR-friendly) ----
  bf16x8 af[2][4];                     // W4h rows (jq*2+jj)*16+la
  bf16x8 af4l[2][4];                   // W4l rows (jq*2+jj)*16+la
  #pragma unroll
  for (int jj = 0; jj < 2; jj++){
    #pragma unroll
    for (int kt = 0; kt < 4; kt++){
      const float* ph = W4 + ((jq*2+jj)*16+la)*384 + kt*32 + g*8;
      const float* pl = W4 + ((jq*2+jj)*16+la)*384 + 128 + kt*32 + g*8;
      af[jj][kt]   = cvt8(*(const float4*)ph, *(const float4*)(ph+4));
      af4l[jj][kt] = cvt8(*(const float4*)pl, *(const float4*)(pl+4));
    }
  }
  bf16x8 af23[2][4];                   // W2h tile w, W3h tile w
  #pragma unroll
  for (int kt = 0; kt < 4; kt++){
    const float* p2 = W2 + (w*16+la)*512 + 384 + kt*32 + g*8;
    const float* p3 = W3 + (w*16+la)*512 + 384 + kt*32 + g*8;
    af23[0][kt] = cvt8(*(const float4*)p2, *(const float4*)(p2+4));
    af23[1][kt] = cvt8(*(const float4*)p3, *(const float4*)(p3+4));
  }

  // ---- precomputed LDS element bases (buffer 0; parity adds HBUF) ----
  // subtiled: elem(c,k) -> ((c>>4)*16 + (k>>3))*128 + (c&15)*8 + (k&7)
  int rb[8], wb[8];
  #pragma unroll
  for (int cg = 0; cg < 8; cg++){
    const int cblk = ch*8 + cg;          // c>>4 for c = ch*128+cg*16+la
    rb[cg] = cblk*2048 + g*128 + la*8;                          // + kt*512
    wb[cg] = cblk*2048 + jq*512 + (g>>1)*128 + la*8 + (g&1)*4;  // + jj*256
  }

  // ---- init staging ----
  if (tid < 128) qsl[tid] = qseq[b*128 + tid];
  __syncthreads();
  const float* pre23b = pre23 + b*127*256;
  const float* pre4b  = pre4  + b*127*128;
  if (tid < 64)       *(float4*)&qeb[tid*4] = *(const float4*)(qmat + (size_t)qsl[0]*256 + tid*4);
  else if (tid < 128) *(float4*)&qeb[256 + (tid-64)*4] = *(const float4*)(qmat + (size_t)qsl[1]*256 + (tid-64)*4);
  else if (tid < 192) *(float4*)&p23L[(tid-128)*4] = *(const float4*)(pre23b + (tid-128)*4);
  else if (tid < 224) *(float4*)&p4L[(tid-192)*4]  = *(const float4*)(pre4b  + (tid-192)*4);

  // h state -> registers (fp32, D-layout) + bf16 shadow buffer 0
  float4 hreg[8][2];
  #pragma unroll
  for (int cg = 0; cg < 8; cg++){
    const int c_ = ch*128 + cg*16 + la;
    #pragma unroll
    for (int jj = 0; jj < 2; jj++){
      const int k0 = (jq*2+jj)*16 + g*4;
      float4 v = *(const float4*)(h0 + c_*128 + k0);
      hreg[cg][jj] = v;
      bf16x4 hb; hb[0]=(__bf16)v.x; hb[1]=(__bf16)v.y; hb[2]=(__bf16)v.z; hb[3]=(__bf16)v.w;
      *(bf16x4*)&hB[wb[cg] + jj*256] = hb;
    }
  }
  __syncthreads();
  // htilde0 = sum_c qe0[c] * h0[c][:]  (register accum + DPP reduce, split store)
  {
    f32x4 r0 = {0.f,0.f,0.f,0.f}, r1 = {0.f,0.f,0.f,0.f};
    #pragma unroll
    for (int cg = 0; cg < 8; cg++){
      const int c_ = ch*128 + cg*16 + la;
      float q = qeb[c_];
      float4 h0v = hreg[cg][0], h1v = hreg[cg][1];
      r0[0] += q*h0v.x; r0[1] += q*h0v.y; r0[2] += q*h0v.z; r0[3] += q*h0v.w;
      r1[0] += q*h1v.x; r1[1] += q*h1v.y; r1[2] += q*h1v.z; r1[3] += q*h1v.w;
    }
    red16(r0); red16(r1);
    if (la == 15){
      float4 s0 = {r0[0],r0[1],r0[2],r0[3]};
      float4 s1 = {r1[0],r1[1],r1[2],r1[3]};
      *(float4*)&htb0[ch*128 + jq*32 + g*4]      = s0;
      *(float4*)&htb0[ch*128 + jq*32 + 16 + g*4] = s1;
    }
  }
  __syncthreads();

  int i0 = 0, i1 = 1, i2 = 2;          // qe triple-buffer rotation

  for (int tau = 0; tau < 127; tau++){
    float* htc = (tau & 1) ? htb1 : htb0;       // [2][128] partials
    float* htn = (tau & 1) ? htb0 : htb1;
    float* qec = qeb + i0*256;
    float* qen = qeb + i1*256;
    float* qep = qeb + i2*256;
    const float* p23c = p23L + (tau & 1)*256;
    const float* p4c  = p4L  + (tau & 1)*128;
    const int roff = (tau & 1) ? HBUF : 0;
    const int woff = (tau & 1) ? 0 : HBUF;

    // ---- P0: m23 via MFMA (hi/lo), LG on all lanes ----
    {
      bf16x8 xh[4], xl[4];
      #pragma unroll
      for (int kt = 0; kt < 4; kt++){
        int k0 = kt*32 + g*8;
        float4 a0 = *(const float4*)&htc[k0];
        float4 a1 = *(const float4*)&htc[k0+4];
        float4 b0 = *(const float4*)&htc[128 + k0];
        float4 b1v = *(const float4*)&htc[128 + k0+4];
        a0.x += b0.x; a0.y += b0.y; a0.z += b0.z; a0.w += b0.w;
        a1.x += b1v.x; a1.y += b1v.y; a1.z += b1v.z; a1.w += b1v.w;
        mk_hilo(a0, a1, xh[kt], xl[kt]);
      }
      f32x4 aLh = {0.f,0.f,0.f,0.f}, aLl = {0.f,0.f,0.f,0.f};
      f32x4 aGh = {0.f,0.f,0.f,0.f}, aGl = {0.f,0.f,0.f,0.f};
      #pragma unroll
      for (int kt = 0; kt < 4; kt++){
        aLh = mfma16(af23[0][kt], xh[kt], aLh);
        aLl = mfma16(af23[0][kt], xl[kt], aLl);
        aGh = mfma16(af23[1][kt], xh[kt], aGh);
        aGl = mfma16(af23[1][kt], xl[kt], aGl);
      }
      float4 lp4 = *(const float4*)&p23c[w*16 + g*4];
      float4 gp4 = *(const float4*)&p23c[128 + w*16 + g*4];
      float4 LG4;
      LG4.x = sigmf(aGh[0]+aGl[0]+gp4.x) * sigmf(2.f*(aLh[0]+aLl[0]+lp4.x));
      LG4.y = sigmf(aGh[1]+aGl[1]+gp4.y) * sigmf(2.f*(aLh[1]+aLl[1]+lp4.y));
      LG4.z = sigmf(aGh[2]+aGl[2]+gp4.z) * sigmf(2.f*(aLh[2]+aLl[2]+lp4.z));
      LG4.w = sigmf(aGh[3]+aGl[3]+gp4.w) * sigmf(2.f*(aLh[3]+aLl[3]+lp4.w));
      if (la == 0){
        *(float4*)&LGb[w*16 + g*4] = LG4;
        bf16x4 lgp;
        lgp[0]=(__bf16)LG4.x; lgp[1]=(__bf16)LG4.y;
        lgp[2]=(__bf16)LG4.z; lgp[3]=(__bf16)LG4.w;
        *(bf16x4*)&LGh[w*16 + g*4] = lgp;
      }
    }
    __syncthreads();                                    // Bb

    // ---- MAIN ----
    // prefetch issue + hist store (hidden under MFMA phase)
    float4 pf23, pf4, pfqe;
    const bool dopf = (tau < 126);
    const bool do23 = dopf && (tid < 64);
    const bool do4  = dopf && (tid >= 64) && (tid < 96);
    const bool doqe = dopf && (tid >= 448);
    if (do23) pf23 = *(const float4*)(pre23b + (tau+1)*256 + tid*4);
    if (do4)  pf4  = *(const float4*)(pre4b  + (tau+1)*128 + (tid-64)*4);
    if (doqe) pfqe = *(const float4*)(qmat + (size_t)qsl[tau+2]*256 + (tid-448)*4);
    if (tau > 0 && tid >= 96 && tid < 128){
      int i = (tid - 96)*4;
      float4 v0 = *(const float4*)&htc[i];
      float4 v1 = *(const float4*)&htc[128 + i];
      float4 v = {v0.x+v1.x, v0.y+v1.y, v0.z+v1.z, v0.w+v1.w};
      *(float4*)(hist + ((size_t)b*127 + (tau-1))*128 + i) = v;
    }

    // z = W4l @ LG + pre4, in-register (rows aligned with update k0)
    float4 z4[2];
    {
      bf16x8 lh[4];
      #pragma unroll
      for (int kt = 0; kt < 4; kt++)
        lh[kt] = *(const bf16x8*)&LGh[kt*32 + g*8];
      #pragma unroll
      for (int jj = 0; jj < 2; jj++){
        f32x4 az = {0.f,0.f,0.f,0.f};
        #pragma unroll
        for (int kt = 0; kt < 4; kt++)
          az = mfma16(af4l[jj][kt], lh[kt], az);
        float4 zp = *(const float4*)&p4c[(jq*2+jj)*16 + g*4];
        z4[jj].x = az[0]+zp.x; z4[jj].y = az[1]+zp.y;
        z4[jj].z = az[2]+zp.z; z4[jj].w = az[3]+zp.w;
      }
    }
    float4 lg4[2];
    #pragma unroll
    for (int jj = 0; jj < 2; jj++)
      lg4[jj] = *(const float4*)&LGb[(jq*2+jj)*16 + g*4];

    // software-pipelined bfv: load cg+1 while computing cg
    bf16x8 bA[4], bB[4];
    {
      const int base = rb[0] + roff;
      #pragma unroll
      for (int kt = 0; kt < 4; kt++) bA[kt] = *(const bf16x8*)&hB[base + kt*512];
    }
    f32x4 r0 = {0.f,0.f,0.f,0.f}, r1 = {0.f,0.f,0.f,0.f};
    #pragma unroll
    for (int cg = 0; cg < 8; cg++){
      const bf16x8* cur = (cg & 1) ? bB : bA;
      bf16x8*       nxt = (cg & 1) ? bA : bB;
      if (cg < 7){
        const int base = rb[cg+1] + roff;
        #pragma unroll
        for (int kt = 0; kt < 4; kt++) nxt[kt] = *(const bf16x8*)&hB[base + kt*512];
      }
      const int c_ = ch*128 + cg*16 + la;
      const float qe_t = qec[c_], qe_n = qen[c_];
      const int wbase = wb[cg] + woff;
      #pragma unroll
      for (int jj = 0; jj < 2; jj++){
        f32x4 acc = {0.f,0.f,0.f,0.f};
        #pragma unroll
        for (int kt = 0; kt < 4; kt++)
          acc = mfma16(af[jj][kt], cur[kt], acc);
        float4 hp = hreg[cg][jj];
        float4 hn;
        hn.x = qe_t*lg4[jj].x + sigmf(acc[0] + z4[jj].x)*hp.x;
        hn.y = qe_t*lg4[jj].y + sigmf(acc[1] + z4[jj].y)*hp.y;
        hn.z = qe_t*lg4[jj].z + sigmf(acc[2] + z4[jj].z)*hp.z;
        hn.w = qe_t*lg4[jj].w + sigmf(acc[3] + z4[jj].w)*hp.w;
        hreg[cg][jj] = hn;
        bf16x4 hb; hb[0]=(__bf16)hn.x; hb[1]=(__bf16)hn.y; hb[2]=(__bf16)hn.z; hb[3]=(__bf16)hn.w;
        *(bf16x4*)&hB[wbase + jj*256] = hb;
        f32x4& r = (jj == 0) ? r0 : r1;
        r[0] += qe_n*hn.x; r[1] += qe_n*hn.y;
        r[2] += qe_n*hn.z; r[3] += qe_n*hn.w;
      }
    }
    // h_tilde: DPP reduce over 16 la-lanes, split plain stores (no atomics)
    red16(r0); red16(r1);
    if (la == 15){
      float4 s0 = {r0[0],r0[1],r0[2],r0[3]};
      float4 s1 = {r1[0],r1[1],r1[2],r1[3]};
      *(float4*)&htn[ch*128 + jq*32 + g*4]      = s0;
      *(float4*)&htn[ch*128 + jq*32 + 16 + g*4] = s1;
    }
    // prefetch writes (different buffers than those read this step)
    if (do23) *(float4*)&p23L[((tau+1)&1)*256 + tid*4] = pf23;
    if (do4)  *(float4*)&p4L[((tau+1)&1)*128 + (tid-64)*4] = pf4;
    if (doqe) *(float4*)&qep[(tid-448)*4] = pfqe;       // qe[tau+2]
    __syncthreads();                                    // B2
    int t_ = i0; i0 = i1; i1 = i2; i2 = t_;
  }

  // ---- epilogue: final h_tilde row, then y for all s (k4 folded) ----
  if (tid < 32){
    int i = tid*4;
    float4 v0 = *(const float4*)&htb1[i];
    float4 v1 = *(const float4*)&htb1[128 + i];
    float4 v = {v0.x+v1.x, v0.y+v1.y, v0.z+v1.z, v0.w+v1.w};
    *(float4*)(hist + ((size_t)b*127 + 126)*128 + i) = v;
  }
  __syncthreads();
  {
    const int j = tid & 127, so = tid >> 7;       // 4 s per chunk
    float* ypart = lds;                           // reuse hB region [8]
    const float* wrow = W5 + j*256 + 128;
    for (int sc = 0; sc < 128; sc += 4){
      int s = sc + so;
      float acc = 0.f;
      if (s > 0){
        const float* xr = hist + ((size_t)b*127 + (s-1))*128;
        acc = pre5[(size_t)(b*128 + s)*128 + j];
        #pragma unroll
        for (int k = 0; k < 128; k += 4){
          float4 wv = *(const float4*)&wrow[k];
          float4 xv = *(const float4*)&xr[k];
          acc += wv.x*xv.x + wv.y*xv.y + wv.z*xv.z + wv.w*xv.w;
        }
        acc = sigmf(acc);
      }
      #pragma unroll
      for (int m = 1; m < 64; m <<= 1) acc += __shfl_xor(acc, m);
      if (lane == 0) ypart[w] = acc;              // w = so*2 + (j>>6)
      __syncthreads();
      if (tid < 4){
        int s2 = sc + tid;
        out[b*128 + s2] = (s2 == 0) ? 0.f
                        : (ypart[tid*2] + ypart[tid*2+1]) * (1.f/128.f);
      }
      __syncthreads();
    }
  }
}

// ---------------- host launch ----------------
extern "C" void kernel_launch(void* const* d_in, const int* in_sizes, int n_in,
                              void* d_out, int out_size, void* d_ws, size_t ws_size,
                              hipStream_t stream) {
  const int*   qseq  = (const int*)  d_in[0];
  const int*   itseq = (const int*)  d_in[1];
  const int*   utseq = (const int*)  d_in[2];
  const float* corr  = (const float*)d_in[3];
  const float* Eq    = (const float*)d_in[4];
  const float* Eit   = (const float*)d_in[5];
  const float* Eut   = (const float*)d_in[6];
  const float* qmat  = (const float*)d_in[7];
  const float* h0    = (const float*)d_in[8];
  const float* W1    = (const float*)d_in[9];
  const float* b1    = (const float*)d_in[10];
  const float* W2    = (const float*)d_in[11];
  const float* b2    = (const float*)d_in[12];
  const float* W3    = (const float*)d_in[13];
  const float* b3    = (const float*)d_in[14];
  const float* W4    = (const float*)d_in[15];
  const float* b4    = (const float*)d_in[16];
  const float* W5    = (const float*)d_in[17];
  const float* b5    = (const float*)d_in[18];
  float* out = (float*)d_out;

  float* ws    = (float*)d_ws;
  float* AL    = ws;                    // 4096*128 ; reused as hist after k2
  float* hist  = ws;                    // 32*127*128 <= AL size
  float* pre5  = ws + 524288;           // 4096*128
  float* pre23 = ws + 1048576;          // 4064*256
  float* pre4  = ws + 2088960;          // 4064*128

  (void)hipFuncSetAttribute(reinterpret_cast<const void*>(&lpkt_scan),
                            hipFuncAttributeMaxDynamicSharedMemorySize,
                            SCAN_LDS_BYTES);

  hipLaunchKernelGGL(k1_al, dim3(64), dim3(256), 0, stream,
                     qseq, utseq, corr, Eq, Eut, W1, b1, W5, b5, AL, pre5);
  hipLaunchKernelGGL(k2_pre, dim3(64), dim3(256), 0, stream,
                     itseq, Eit, AL, W2, W3, W4, b2, b3, b4, pre23, pre4);
  hipLaunchKernelGGL(lpkt_scan, dim3(32), dim3(512), SCAN_LDS_BYTES, stream,
                     qmat, qseq, h0, W2, W3, W4, W5, pre23, pre4, pre5,
                     hist, out);
}

// Round 11
// 819.877 us; speedup vs baseline: 2.2466x; 1.3266x over previous
//
#include <hip/hip_runtime.h>
#include <hip/hip_bf16.h>

// LPKT+ forward. B=32, S=128, C=256, K=128, DC=128, T=127 scan steps.
// Round-7 configuration (measured best: 824 us total, scan 650 us).
//
//  K1: AL = [eq|eut]@W1a^T + b1 + correct*rs1c ; pre5 = eq@W5q^T + b5
//  K2: pre23 = [AL[t-1]|it|AL[t]] @ [W2a|W3a]^T + b ; pre4 = it@W4i^T + b4
//  K3 (scan): 32 blocks x 512 threads (8 waves = 4 j-quarters x 2 col-halves).
//      h fp32 in registers + bf16 shadow in LDS, dbuf, SUBTILED layout
//      [c/16][k/8][c%16][8] -> b128 reads and b64 writes conflict-free by
//      construction; base+imm addressing. h_tilde reduced with DPP row_shr
//      (VALU pipe) + split plain stores. 2 barriers/step.
//  K4: batched y = mean_j sigmoid(pre5 + W5h @ ht_hist).

typedef __bf16 bf16x8 __attribute__((ext_vector_type(8)));
typedef __bf16 bf16x4 __attribute__((ext_vector_type(4)));
typedef float f32x4 __attribute__((ext_vector_type(4)));

#define HBUF 32768               // elems per h-shadow buffer (256x128 bf16)

__device__ __forceinline__ float sigmf(float x){
  return __builtin_amdgcn_rcpf(1.0f + __expf(-x));
}

__device__ __forceinline__ bf16x8 cvt8(float4 a, float4 b){
  bf16x8 r;
  r[0]=(__bf16)a.x; r[1]=(__bf16)a.y; r[2]=(__bf16)a.z; r[3]=(__bf16)a.w;
  r[4]=(__bf16)b.x; r[5]=(__bf16)b.y; r[6]=(__bf16)b.z; r[7]=(__bf16)b.w;
  return r;
}

// hi/lo bf16 split of 8 fp32 values (fp32-grade MFMA input)
__device__ __forceinline__ void mk_hilo(float4 a, float4 b, bf16x8& hi, bf16x8& lo){
  float v[8] = {a.x,a.y,a.z,a.w,b.x,b.y,b.z,b.w};
  #pragma unroll
  for (int i = 0; i < 8; i++){
    __bf16 h = (__bf16)v[i];
    hi[i] = h;
    lo[i] = (__bf16)(v[i] - (float)h);
  }
}

__device__ __forceinline__ f32x4 mfma16(bf16x8 a, bf16x8 b, f32x4 c){
  return __builtin_amdgcn_mfma_f32_16x16x32_bf16(a, b, c, 0, 0, 0);
}

// sum over each row of 16 lanes via DPP row_shr (VALU, not LDS pipe).
// Result valid in lane la==15 of each row.
__device__ __forceinline__ float dpp_sum16(float v){
  int x;
  x = __builtin_amdgcn_update_dpp(0, __builtin_bit_cast(int, v), 0x111, 0xf, 0xf, true);
  v += __builtin_bit_cast(float, x);
  x = __builtin_amdgcn_update_dpp(0, __builtin_bit_cast(int, v), 0x112, 0xf, 0xf, true);
  v += __builtin_bit_cast(float, x);
  x = __builtin_amdgcn_update_dpp(0, __builtin_bit_cast(int, v), 0x114, 0xf, 0xf, true);
  v += __builtin_bit_cast(float, x);
  x = __builtin_amdgcn_update_dpp(0, __builtin_bit_cast(int, v), 0x118, 0xf, 0xf, true);
  v += __builtin_bit_cast(float, x);
  return v;
}

__device__ __forceinline__ void red16(f32x4& r){
  r[0] = dpp_sum16(r[0]);
  r[1] = dpp_sum16(r[1]);
  r[2] = dpp_sum16(r[2]);
  r[3] = dpp_sum16(r[3]);
}

// ---------------- K1 ----------------
__global__ __launch_bounds__(256) void k1_al(
    const int* __restrict__ qseq, const int* __restrict__ utseq,
    const float* __restrict__ corr,
    const float* __restrict__ Eq, const float* __restrict__ Eut,
    const float* __restrict__ W1, const float* __restrict__ b1,
    const float* __restrict__ W5, const float* __restrict__ b5,
    float* __restrict__ AL, float* __restrict__ pre5)
{
  __shared__ __bf16 inA[64*256];
  __shared__ float corrs[64];
  __shared__ float b1s[128], b5s[128], rsp[256];
  const int tid = threadIdx.x, blk = blockIdx.x;
  if (tid < 128){ b1s[tid]=b1[tid]; b5s[tid]=b5[tid]; }
  { // rs1c partial sums
    int j = tid & 127, hf = tid >> 7;
    const float* p = W1 + j*384 + 256 + hf*64;
    float s = 0.f;
    for (int i = 0; i < 64; i++) s += p[i];
    rsp[tid] = s;
  }
  {
    int r = tid >> 2, seg = tid & 3;
    int R = blk*64 + r;
    int qi = qseq[R], ui = utseq[R];
    if (seg == 0) corrs[r] = corr[R];
    for (int i = 0; i < 64; i++){
      int col = seg*64 + i;
      float v = (col < 128) ? Eq[qi*128 + col] : Eut[ui*128 + (col-128)];
      inA[((r*256 + col) ^ ((r&7)<<3))] = (__bf16)v;
    }
  }
  __syncthreads();
  const int w = tid >> 6, lane = tid & 63;
  const int la = lane & 15, g = lane >> 4;
  const int rbase = w*16;
  bf16x8 af[8];
  #pragma unroll
  for (int kt = 0; kt < 8; kt++){
    int idx = ((rbase+la)*256 + kt*32 + g*8) ^ ((la&7)<<3);
    af[kt] = *(const bf16x8*)&inA[idx];
  }
  for (int jt = 0; jt < 8; jt++){
    f32x4 acc = {0.f,0.f,0.f,0.f};
    const float* Wb = W1 + (jt*16+la)*384;
    #pragma unroll
    for (int kt = 0; kt < 8; kt++){
      const float* p = Wb + kt*32 + g*8;
      acc = mfma16(af[kt], cvt8(*(const float4*)p, *(const float4*)(p+4)), acc);
    }
    int j = jt*16 + la;
    float rsj = rsp[j] + rsp[j+128];
    #pragma unroll
    for (int rr = 0; rr < 4; rr++){
      int row = rbase + g*4 + rr;
      int R = blk*64 + row;
      AL[R*128 + j] = acc[rr] + b1s[j] + corrs[row]*rsj;
    }
  }
  for (int jt = 0; jt < 8; jt++){
    f32x4 acc = {0.f,0.f,0.f,0.f};
    const float* Wb = W5 + (jt*16+la)*256;
    #pragma unroll
    for (int kt = 0; kt < 4; kt++){
      const float* p = Wb + kt*32 + g*8;
      acc = mfma16(af[kt], cvt8(*(const float4*)p, *(const float4*)(p+4)), acc);
    }
    int j = jt*16 + la;
    #pragma unroll
    for (int rr = 0; rr < 4; rr++){
      int row = rbase + g*4 + rr;
      int R = blk*64 + row;
      pre5[R*128 + j] = acc[rr] + b5s[j];
    }
  }
}

// ---------------- K2 ----------------
__global__ __launch_bounds__(256) void k2_pre(
    const int* __restrict__ itseq, const float* __restrict__ Eit,
    const float* __restrict__ AL,
    const float* __restrict__ W2, const float* __restrict__ W3,
    const float* __restrict__ W4,
    const float* __restrict__ b2, const float* __restrict__ b3,
    const float* __restrict__ b4,
    float* __restrict__ pre23, float* __restrict__ pre4)
{
  __shared__ __bf16 inA[64*384];
  __shared__ int obase[64];
  __shared__ float b2s[128], b3s[128], b4s[128];
  const int tid = threadIdx.x, blk = blockIdx.x;
  if (tid < 128){ b2s[tid]=b2[tid]; b3s[tid]=b3[tid]; b4s[tid]=b4[tid]; }
  {
    int r = tid >> 2, seg = tid & 3;
    int R = blk*64 + r;
    bool valid = (R < 4064);
    int b_ = R / 127, tau = R % 127;
    if (seg == 0) obase[r] = valid ? (b_*127 + tau) : -1;
    int itv = valid ? itseq[b_*128 + tau] : 0;
    for (int i = 0; i < 96; i++){
      int col = seg*96 + i;
      float v = 0.f;
      if (valid){
        if (col < 128)      v = (tau > 0) ? AL[(b_*128 + tau-1)*128 + col] : 0.f;
        else if (col < 256) v = Eit[itv*128 + (col-128)];
        else                v = AL[(b_*128 + tau)*128 + (col-256)];
      }
      inA[((r*384 + col) ^ ((r&7)<<3))] = (__bf16)v;
    }
  }
  __syncthreads();
  const int w = tid >> 6, lane = tid & 63;
  const int la = lane & 15, g = lane >> 4;
  const int rbase = w*16;
  bf16x8 af[12];
  #pragma unroll
  for (int kt = 0; kt < 12; kt++){
    int idx = ((rbase+la)*384 + kt*32 + g*8) ^ ((la&7)<<3);
    af[kt] = *(const bf16x8*)&inA[idx];
  }
  for (int jt = 0; jt < 16; jt++){
    f32x4 acc = {0.f,0.f,0.f,0.f};
    int j = jt*16 + la;
    const float* Wb = (j < 128) ? (W2 + j*512) : (W3 + (j-128)*512);
    #pragma unroll
    for (int kt = 0; kt < 12; kt++){
      const float* p = Wb + kt*32 + g*8;
      acc = mfma16(af[kt], cvt8(*(const float4*)p, *(const float4*)(p+4)), acc);
    }
    float bias = (j < 128) ? b2s[j] : b3s[j-128];
    #pragma unroll
    for (int rr = 0; rr < 4; rr++){
      int row = rbase + g*4 + rr;
      int ob = obase[row];
      if (ob >= 0) pre23[ob*256 + j] = acc[rr] + bias;
    }
  }
  for (int jt = 0; jt < 8; jt++){
    f32x4 acc = {0.f,0.f,0.f,0.f};
    int j = jt*16 + la;
    const float* Wb = W4 + j*384 + 256;
    #pragma unroll
    for (int kk = 0; kk < 4; kk++){
      const float* p = Wb + kk*32 + g*8;
      acc = mfma16(af[4+kk], cvt8(*(const float4*)p, *(const float4*)(p+4)), acc);
    }
    #pragma unroll
    for (int rr = 0; rr < 4; rr++){
      int row = rbase + g*4 + rr;
      int ob = obase[row];
      if (ob >= 0) pre4[ob*128 + j] = acc[rr] + b4s[j];
    }
  }
}

// ---------------- K3: scan, 32 blocks x 512 threads ----------------
// LDS floats: hB bf16 2x32768 = 32768 f | htb0[2][128] 256 | htb1[2][128] 256 |
//   LGb 128 | LGh(bf16) 64 | qeb[3][256] 768 | p23L[2][256] 512 |
//   p4L[2][128] 256 | qsl(int) 128 => 35136 f = 140544 B
#define SCAN_LDS_BYTES (35136*4)

__global__ __launch_bounds__(512, 2) void lpkt_scan(
    const float* __restrict__ qmat, const int* __restrict__ qseq,
    const float* __restrict__ h0,
    const float* __restrict__ W2, const float* __restrict__ W3,
    const float* __restrict__ W4,
    const float* __restrict__ pre23, const float* __restrict__ pre4,
    float* __restrict__ hist)
{
  extern __shared__ float lds[];
  __bf16* hB   = (__bf16*)lds;            // 2 x subtiled 256x128
  float*  htb0 = lds + 32768;             // [2][128]
  float*  htb1 = lds + 33024;             // [2][128]
  float*  LGb  = lds + 33280;             // fp32 LG
  __bf16* LGh  = (__bf16*)(lds + 33408);  // bf16 LG
  float*  qeb  = lds + 33472;             // [3][256]
  float*  p23L = lds + 34240;             // [2][256]
  float*  p4L  = lds + 34752;             // [2][128]
  int*    qsl  = (int*)(lds + 35008);

  const int tid  = threadIdx.x;
  const int b    = blockIdx.x;
  const int lane = tid & 63;
  const int w    = tid >> 6;           // 8 waves
  const int la   = lane & 15, g = lane >> 4;
  const int jq   = w & 3;              // j-quarter of k-dim outputs
  const int ch   = w >> 2;             // column half (128 columns)

  // ---- persistent register weight fragments (MFMA-A -> AGPR-friendly) ----
  bf16x8 af[2][4];                     // W4h rows (jq*2+jj)*16+la
  bf16x8 af4l[2][4];                   // W4l rows (jq*2+jj)*16+la
  #pragma unroll
  for (int jj = 0; jj < 2; jj++){
    #pragma unroll
    for (int kt = 0; kt < 4; kt++){
      const float* ph = W4 + ((jq*2+jj)*16+la)*384 + kt*32 + g*8;
      const float* pl = W4 + ((jq*2+jj)*16+la)*384 + 128 + kt*32 + g*8;
      af[jj][kt]   = cvt8(*(const float4*)ph, *(const float4*)(ph+4));
      af4l[jj][kt] = cvt8(*(const float4*)pl, *(const float4*)(pl+4));
    }
  }
  bf16x8 af23[2][4];                   // W2h tile w, W3h tile w
  #pragma unroll
  for (int kt = 0; kt < 4; kt++){
    const float* p2 = W2 + (w*16+la)*512 + 384 + kt*32 + g*8;
    const float* p3 = W3 + (w*16+la)*512 + 384 + kt*32 + g*8;
    af23[0][kt] = cvt8(*(const float4*)p2, *(const float4*)(p2+4));
    af23[1][kt] = cvt8(*(const float4*)p3, *(const float4*)(p3+4));
  }

  // ---- precomputed LDS element bases (buffer 0; parity adds HBUF) ----
  // subtiled: elem(c,k) -> ((c>>4)*16 + (k>>3))*128 + (c&15)*8 + (k&7)
  int rb[8], wb[8];
  #pragma unroll
  for (int cg = 0; cg < 8; cg++){
    const int cblk = ch*8 + cg;          // c>>4 for c = ch*128+cg*16+la
    rb[cg] = cblk*2048 + g*128 + la*8;                          // + kt*512
    wb[cg] = cblk*2048 + jq*512 + (g>>1)*128 + la*8 + (g&1)*4;  // + jj*256
  }

  // ---- init staging ----
  if (tid < 128) qsl[tid] = qseq[b*128 + tid];
  __syncthreads();
  const float* pre23b = pre23 + b*127*256;
  const float* pre4b  = pre4  + b*127*128;
  if (tid < 64)       *(float4*)&qeb[tid*4] = *(const float4*)(qmat + (size_t)qsl[0]*256 + tid*4);
  else if (tid < 128) *(float4*)&qeb[256 + (tid-64)*4] = *(const float4*)(qmat + (size_t)qsl[1]*256 + (tid-64)*4);
  else if (tid < 192) *(float4*)&p23L[(tid-128)*4] = *(const float4*)(pre23b + (tid-128)*4);
  else if (tid < 224) *(float4*)&p4L[(tid-192)*4]  = *(const float4*)(pre4b  + (tid-192)*4);

  // h state -> registers (fp32, D-layout) + bf16 shadow buffer 0
  float4 hreg[8][2];
  #pragma unroll
  for (int cg = 0; cg < 8; cg++){
    const int c_ = ch*128 + cg*16 + la;
    #pragma unroll
    for (int jj = 0; jj < 2; jj++){
      const int k0 = (jq*2+jj)*16 + g*4;
      float4 v = *(const float4*)(h0 + c_*128 + k0);
      hreg[cg][jj] = v;
      bf16x4 hb; hb[0]=(__bf16)v.x; hb[1]=(__bf16)v.y; hb[2]=(__bf16)v.z; hb[3]=(__bf16)v.w;
      *(bf16x4*)&hB[wb[cg] + jj*256] = hb;
    }
  }
  __syncthreads();
  // htilde0 = sum_c qe0[c] * h0[c][:]  (register accum + DPP reduce, split store)
  {
    f32x4 r0 = {0.f,0.f,0.f,0.f}, r1 = {0.f,0.f,0.f,0.f};
    #pragma unroll
    for (int cg = 0; cg < 8; cg++){
      const int c_ = ch*128 + cg*16 + la;
      float q = qeb[c_];
      float4 h0v = hreg[cg][0], h1v = hreg[cg][1];
      r0[0] += q*h0v.x; r0[1] += q*h0v.y; r0[2] += q*h0v.z; r0[3] += q*h0v.w;
      r1[0] += q*h1v.x; r1[1] += q*h1v.y; r1[2] += q*h1v.z; r1[3] += q*h1v.w;
    }
    red16(r0); red16(r1);
    if (la == 15){
      float4 s0 = {r0[0],r0[1],r0[2],r0[3]};
      float4 s1 = {r1[0],r1[1],r1[2],r1[3]};
      *(float4*)&htb0[ch*128 + jq*32 + g*4]      = s0;
      *(float4*)&htb0[ch*128 + jq*32 + 16 + g*4] = s1;
    }
  }
  __syncthreads();

  int i0 = 0, i1 = 1, i2 = 2;          // qe triple-buffer rotation

  for (int tau = 0; tau < 127; tau++){
    float* htc = (tau & 1) ? htb1 : htb0;       // [2][128] partials
    float* htn = (tau & 1) ? htb0 : htb1;
    float* qec = qeb + i0*256;
    float* qen = qeb + i1*256;
    float* qep = qeb + i2*256;
    const float* p23c = p23L + (tau & 1)*256;
    const float* p4c  = p4L  + (tau & 1)*128;
    const int roff = (tau & 1) ? HBUF : 0;
    const int woff = (tau & 1) ? 0 : HBUF;

    // ---- P0: m23 via MFMA (hi/lo), LG on all lanes ----
    {
      bf16x8 xh[4], xl[4];
      #pragma unroll
      for (int kt = 0; kt < 4; kt++){
        int k0 = kt*32 + g*8;
        float4 a0 = *(const float4*)&htc[k0];
        float4 a1 = *(const float4*)&htc[k0+4];
        float4 b0 = *(const float4*)&htc[128 + k0];
        float4 b1v = *(const float4*)&htc[128 + k0+4];
        a0.x += b0.x; a0.y += b0.y; a0.z += b0.z; a0.w += b0.w;
        a1.x += b1v.x; a1.y += b1v.y; a1.z += b1v.z; a1.w += b1v.w;
        mk_hilo(a0, a1, xh[kt], xl[kt]);
      }
      f32x4 aLh = {0.f,0.f,0.f,0.f}, aLl = {0.f,0.f,0.f,0.f};
      f32x4 aGh = {0.f,0.f,0.f,0.f}, aGl = {0.f,0.f,0.f,0.f};
      #pragma unroll
      for (int kt = 0; kt < 4; kt++){
        aLh = mfma16(af23[0][kt], xh[kt], aLh);
        aLl = mfma16(af23[0][kt], xl[kt], aLl);
        aGh = mfma16(af23[1][kt], xh[kt], aGh);
        aGl = mfma16(af23[1][kt], xl[kt], aGl);
      }
      float4 lp4 = *(const float4*)&p23c[w*16 + g*4];
      float4 gp4 = *(const float4*)&p23c[128 + w*16 + g*4];
      float4 LG4;
      LG4.x = sigmf(aGh[0]+aGl[0]+gp4.x) * sigmf(2.f*(aLh[0]+aLl[0]+lp4.x));
      LG4.y = sigmf(aGh[1]+aGl[1]+gp4.y) * sigmf(2.f*(aLh[1]+aLl[1]+lp4.y));
      LG4.z = sigmf(aGh[2]+aGl[2]+gp4.z) * sigmf(2.f*(aLh[2]+aLl[2]+lp4.z));
      LG4.w = sigmf(aGh[3]+aGl[3]+gp4.w) * sigmf(2.f*(aLh[3]+aLl[3]+lp4.w));
      if (la == 0){
        *(float4*)&LGb[w*16 + g*4] = LG4;
        bf16x4 lgp;
        lgp[0]=(__bf16)LG4.x; lgp[1]=(__bf16)LG4.y;
        lgp[2]=(__bf16)LG4.z; lgp[3]=(__bf16)LG4.w;
        *(bf16x4*)&LGh[w*16 + g*4] = lgp;
      }
    }
    __syncthreads();                                    // Bb

    // ---- MAIN ----
    // prefetch issue + hist store (hidden under MFMA phase)
    float4 pf23, pf4, pfqe;
    const bool dopf = (tau < 126);
    const bool do23 = dopf && (tid < 64);
    const bool do4  = dopf && (tid >= 64) && (tid < 96);
    const bool doqe = dopf && (tid >= 448);
    if (do23) pf23 = *(const float4*)(pre23b + (tau+1)*256 + tid*4);
    if (do4)  pf4  = *(const float4*)(pre4b  + (tau+1)*128 + (tid-64)*4);
    if (doqe) pfqe = *(const float4*)(qmat + (size_t)qsl[tau+2]*256 + (tid-448)*4);
    if (tau > 0 && tid >= 96 && tid < 128){
      int i = (tid - 96)*4;
      float4 v0 = *(const float4*)&htc[i];
      float4 v1 = *(const float4*)&htc[128 + i];
      float4 v = {v0.x+v1.x, v0.y+v1.y, v0.z+v1.z, v0.w+v1.w};
      *(float4*)(hist + ((size_t)b*127 + (tau-1))*128 + i) = v;
    }

    // z = W4l @ LG + pre4, in-register (rows aligned with update k0)
    float4 z4[2];
    {
      bf16x8 lh[4];
      #pragma unroll
      for (int kt = 0; kt < 4; kt++)
        lh[kt] = *(const bf16x8*)&LGh[kt*32 + g*8];
      #pragma unroll
      for (int jj = 0; jj < 2; jj++){
        f32x4 az = {0.f,0.f,0.f,0.f};
        #pragma unroll
        for (int kt = 0; kt < 4; kt++)
          az = mfma16(af4l[jj][kt], lh[kt], az);
        float4 zp = *(const float4*)&p4c[(jq*2+jj)*16 + g*4];
        z4[jj].x = az[0]+zp.x; z4[jj].y = az[1]+zp.y;
        z4[jj].z = az[2]+zp.z; z4[jj].w = az[3]+zp.w;
      }
    }
    float4 lg4[2];
    #pragma unroll
    for (int jj = 0; jj < 2; jj++)
      lg4[jj] = *(const float4*)&LGb[(jq*2+jj)*16 + g*4];

    // software-pipelined bfv: load cg+1 while computing cg
    bf16x8 bA[4], bB[4];
    {
      const int base = rb[0] + roff;
      #pragma unroll
      for (int kt = 0; kt < 4; kt++) bA[kt] = *(const bf16x8*)&hB[base + kt*512];
    }
    f32x4 r0 = {0.f,0.f,0.f,0.f}, r1 = {0.f,0.f,0.f,0.f};
    #pragma unroll
    for (int cg = 0; cg < 8; cg++){
      const bf16x8* cur = (cg & 1) ? bB : bA;
      bf16x8*       nxt = (cg & 1) ? bA : bB;
      if (cg < 7){
        const int base = rb[cg+1] + roff;
        #pragma unroll
        for (int kt = 0; kt < 4; kt++) nxt[kt] = *(const bf16x8*)&hB[base + kt*512];
      }
      const int c_ = ch*128 + cg*16 + la;
      const float qe_t = qec[c_], qe_n = qen[c_];
      const int wbase = wb[cg] + woff;
      #pragma unroll
      for (int jj = 0; jj < 2; jj++){
        f32x4 acc = {0.f,0.f,0.f,0.f};
        #pragma unroll
        for (int kt = 0; kt < 4; kt++)
          acc = mfma16(af[jj][kt], cur[kt], acc);
        float4 hp = hreg[cg][jj];
        float4 hn;
        hn.x = qe_t*lg4[jj].x + sigmf(acc[0] + z4[jj].x)*hp.x;
        hn.y = qe_t*lg4[jj].y + sigmf(acc[1] + z4[jj].y)*hp.y;
        hn.z = qe_t*lg4[jj].z + sigmf(acc[2] + z4[jj].z)*hp.z;
        hn.w = qe_t*lg4[jj].w + sigmf(acc[3] + z4[jj].w)*hp.w;
        hreg[cg][jj] = hn;
        bf16x4 hb; hb[0]=(__bf16)hn.x; hb[1]=(__bf16)hn.y; hb[2]=(__bf16)hn.z; hb[3]=(__bf16)hn.w;
        *(bf16x4*)&hB[wbase + jj*256] = hb;
        f32x4& r = (jj == 0) ? r0 : r1;
        r[0] += qe_n*hn.x; r[1] += qe_n*hn.y;
        r[2] += qe_n*hn.z; r[3] += qe_n*hn.w;
      }
    }
    // h_tilde: DPP reduce over 16 la-lanes, split plain stores (no atomics)
    red16(r0); red16(r1);
    if (la == 15){
      float4 s0 = {r0[0],r0[1],r0[2],r0[3]};
      float4 s1 = {r1[0],r1[1],r1[2],r1[3]};
      *(float4*)&htn[ch*128 + jq*32 + g*4]      = s0;
      *(float4*)&htn[ch*128 + jq*32 + 16 + g*4] = s1;
    }
    // prefetch writes (different buffers than those read this step)
    if (do23) *(float4*)&p23L[((tau+1)&1)*256 + tid*4] = pf23;
    if (do4)  *(float4*)&p4L[((tau+1)&1)*128 + (tid-64)*4] = pf4;
    if (doqe) *(float4*)&qep[(tid-448)*4] = pfqe;       // qe[tau+2]
    __syncthreads();                                    // B2
    int t_ = i0; i0 = i1; i1 = i2; i2 = t_;
  }

  // epilogue: store final h_tilde (htn of tau=126 lives in htb1)
  if (tid < 32){
    int i = tid*4;
    float4 v0 = *(const float4*)&htb1[i];
    float4 v1 = *(const float4*)&htb1[128 + i];
    float4 v = {v0.x+v1.x, v0.y+v1.y, v0.z+v1.z, v0.w+v1.w};
    *(float4*)(hist + ((size_t)b*127 + 126)*128 + i) = v;
  }
}

// ---------------- K4: batched y ----------------
__global__ __launch_bounds__(128) void k4_y(
    const float* __restrict__ hist, const float* __restrict__ pre5,
    const float* __restrict__ W5, float* __restrict__ out)
{
  const int R = blockIdx.x;            // 0..4095 = b*128+s
  const int s = R & 127, b = R >> 7;
  const int j = threadIdx.x;
  __shared__ float xs[128];
  __shared__ float partial[2];
  if (s == 0){ if (j == 0) out[R] = 0.f; return; }
  xs[j] = hist[((size_t)b*127 + (s-1))*128 + j];
  __syncthreads();
  const float* wr = W5 + j*256 + 128;
  float acc = pre5[(size_t)R*128 + j];
  #pragma unroll
  for (int k = 0; k < 128; k += 4){
    float4 wv = *(const float4*)&wr[k];
    float4 xv = *(const float4*)&xs[k];
    acc += wv.x*xv.x + wv.y*xv.y + wv.z*xv.z + wv.w*xv.w;
  }
  float v = sigmf(acc);
  #pragma unroll
  for (int m = 1; m < 64; m <<= 1) v += __shfl_xor(v, m);
  if ((j & 63) == 0) partial[j >> 6] = v;
  __syncthreads();
  if (j == 0) out[R] = (partial[0] + partial[1]) * (1.f/128.f);
}

// ---------------- host launch ----------------
extern "C" void kernel_launch(void* const* d_in, const int* in_sizes, int n_in,
                              void* d_out, int out_size, void* d_ws, size_t ws_size,
                              hipStream_t stream) {
  const int*   qseq  = (const int*)  d_in[0];
  const int*   itseq = (const int*)  d_in[1];
  const int*   utseq = (const int*)  d_in[2];
  const float* corr  = (const float*)d_in[3];
  const float* Eq    = (const float*)d_in[4];
  const float* Eit   = (const float*)d_in[5];
  const float* Eut   = (const float*)d_in[6];
  const float* qmat  = (const float*)d_in[7];
  const float* h0    = (const float*)d_in[8];
  const float* W1    = (const float*)d_in[9];
  const float* b1    = (const float*)d_in[10];
  const float* W2    = (const float*)d_in[11];
  const float* b2    = (const float*)d_in[12];
  const float* W3    = (const float*)d_in[13];
  const float* b3    = (const float*)d_in[14];
  const float* W4    = (const float*)d_in[15];
  const float* b4    = (const float*)d_in[16];
  const float* W5    = (const float*)d_in[17];
  const float* b5    = (const float*)d_in[18];
  float* out = (float*)d_out;

  float* ws    = (float*)d_ws;
  float* AL    = ws;                    // 4096*128 ; reused as hist after k2
  float* hist  = ws;                    // 32*127*128 <= AL size
  float* pre5  = ws + 524288;           // 4096*128
  float* pre23 = ws + 1048576;          // 4064*256
  float* pre4  = ws + 2088960;          // 4064*128

  (void)hipFuncSetAttribute(reinterpret_cast<const void*>(&lpkt_scan),
                            hipFuncAttributeMaxDynamicSharedMemorySize,
                            SCAN_LDS_BYTES);

  hipLaunchKernelGGL(k1_al, dim3(64), dim3(256), 0, stream,
                     qseq, utseq, corr, Eq, Eut, W1, b1, W5, b5, AL, pre5);
  hipLaunchKernelGGL(k2_pre, dim3(64), dim3(256), 0, stream,
                     itseq, Eit, AL, W2, W3, W4, b2, b3, b4, pre23, pre4);
  hipLaunchKernelGGL(lpkt_scan, dim3(32), dim3(512), SCAN_LDS_BYTES, stream,
                     qmat, qseq, h0, W2, W3, W4, pre23, pre4, hist);
  hipLaunchKernelGGL(k4_y, dim3(4096), dim3(128), 0, stream,
                     hist, pre5, W5, out);
}

// Round 12
// 778.171 us; speedup vs baseline: 2.3670x; 1.0536x over previous
//
#include <hip/hip_runtime.h>
#include <hip/hip_bf16.h>

// LPKT+ forward. B=32, S=128, C=256, K=128, DC=128, T=127 scan steps.
// Scan = round-7/11 configuration (reproduced best: 650 us dispatch).
// This round: vectorized k1/k2 staging + k4 as MFMA GEMM. Scan untouched.

typedef __bf16 bf16x8 __attribute__((ext_vector_type(8)));
typedef __bf16 bf16x4 __attribute__((ext_vector_type(4)));
typedef float f32x4 __attribute__((ext_vector_type(4)));

#define HBUF 32768               // elems per h-shadow buffer (256x128 bf16)

__device__ __forceinline__ float sigmf(float x){
  return __builtin_amdgcn_rcpf(1.0f + __expf(-x));
}

__device__ __forceinline__ bf16x8 cvt8(float4 a, float4 b){
  bf16x8 r;
  r[0]=(__bf16)a.x; r[1]=(__bf16)a.y; r[2]=(__bf16)a.z; r[3]=(__bf16)a.w;
  r[4]=(__bf16)b.x; r[5]=(__bf16)b.y; r[6]=(__bf16)b.z; r[7]=(__bf16)b.w;
  return r;
}

// hi/lo bf16 split of 8 fp32 values (fp32-grade MFMA input)
__device__ __forceinline__ void mk_hilo(float4 a, float4 b, bf16x8& hi, bf16x8& lo){
  float v[8] = {a.x,a.y,a.z,a.w,b.x,b.y,b.z,b.w};
  #pragma unroll
  for (int i = 0; i < 8; i++){
    __bf16 h = (__bf16)v[i];
    hi[i] = h;
    lo[i] = (__bf16)(v[i] - (float)h);
  }
}

__device__ __forceinline__ f32x4 mfma16(bf16x8 a, bf16x8 b, f32x4 c){
  return __builtin_amdgcn_mfma_f32_16x16x32_bf16(a, b, c, 0, 0, 0);
}

// sum over each row of 16 lanes via DPP row_shr (VALU, not LDS pipe).
// Result valid in lane la==15 of each row.
__device__ __forceinline__ float dpp_sum16(float v){
  int x;
  x = __builtin_amdgcn_update_dpp(0, __builtin_bit_cast(int, v), 0x111, 0xf, 0xf, true);
  v += __builtin_bit_cast(float, x);
  x = __builtin_amdgcn_update_dpp(0, __builtin_bit_cast(int, v), 0x112, 0xf, 0xf, true);
  v += __builtin_bit_cast(float, x);
  x = __builtin_amdgcn_update_dpp(0, __builtin_bit_cast(int, v), 0x114, 0xf, 0xf, true);
  v += __builtin_bit_cast(float, x);
  x = __builtin_amdgcn_update_dpp(0, __builtin_bit_cast(int, v), 0x118, 0xf, 0xf, true);
  v += __builtin_bit_cast(float, x);
  return v;
}

__device__ __forceinline__ void red16(f32x4& r){
  r[0] = dpp_sum16(r[0]);
  r[1] = dpp_sum16(r[1]);
  r[2] = dpp_sum16(r[2]);
  r[3] = dpp_sum16(r[3]);
}

// ---------------- K1 ----------------
__global__ __launch_bounds__(256) void k1_al(
    const int* __restrict__ qseq, const int* __restrict__ utseq,
    const float* __restrict__ corr,
    const float* __restrict__ Eq, const float* __restrict__ Eut,
    const float* __restrict__ W1, const float* __restrict__ b1,
    const float* __restrict__ W5, const float* __restrict__ b5,
    float* __restrict__ AL, float* __restrict__ pre5)
{
  __shared__ __bf16 inA[64*256];
  __shared__ float corrs[64];
  __shared__ float b1s[128], b5s[128], rsp[256];
  const int tid = threadIdx.x, blk = blockIdx.x;
  if (tid < 128){ b1s[tid]=b1[tid]; b5s[tid]=b5[tid]; }
  { // rs1c partial sums
    int j = tid & 127, hf = tid >> 7;
    const float* p = W1 + j*384 + 256 + hf*64;
    float s = 0.f;
    for (int i = 0; i < 64; i++) s += p[i];
    rsp[tid] = s;
  }
  { // vectorized staging: 8 x (float4-pair -> bf16x8)
    int r = tid >> 2, seg = tid & 3;
    int R = blk*64 + r;
    int qi = qseq[R], ui = utseq[R];
    if (seg == 0) corrs[r] = corr[R];
    const float* eq = Eq + (size_t)qi*128;
    const float* eu = Eut + (size_t)ui*128;
    #pragma unroll
    for (int i8 = 0; i8 < 8; i8++){
      int col0 = seg*64 + i8*8;
      const float* src = (col0 < 128) ? (eq + col0) : (eu + col0 - 128);
      bf16x8 v = cvt8(*(const float4*)src, *(const float4*)(src+4));
      *(bf16x8*)&inA[(r*256 + col0) ^ ((r&7)<<3)] = v;
    }
  }
  __syncthreads();
  const int w = tid >> 6, lane = tid & 63;
  const int la = lane & 15, g = lane >> 4;
  const int rbase = w*16;
  bf16x8 af[8];
  #pragma unroll
  for (int kt = 0; kt < 8; kt++){
    int idx = ((rbase+la)*256 + kt*32 + g*8) ^ ((la&7)<<3);
    af[kt] = *(const bf16x8*)&inA[idx];
  }
  for (int jt = 0; jt < 8; jt++){
    f32x4 acc = {0.f,0.f,0.f,0.f};
    const float* Wb = W1 + (jt*16+la)*384;
    #pragma unroll
    for (int kt = 0; kt < 8; kt++){
      const float* p = Wb + kt*32 + g*8;
      acc = mfma16(af[kt], cvt8(*(const float4*)p, *(const float4*)(p+4)), acc);
    }
    int j = jt*16 + la;
    float rsj = rsp[j] + rsp[j+128];
    #pragma unroll
    for (int rr = 0; rr < 4; rr++){
      int row = rbase + g*4 + rr;
      int R = blk*64 + row;
      AL[R*128 + j] = acc[rr] + b1s[j] + corrs[row]*rsj;
    }
  }
  for (int jt = 0; jt < 8; jt++){
    f32x4 acc = {0.f,0.f,0.f,0.f};
    const float* Wb = W5 + (jt*16+la)*256;
    #pragma unroll
    for (int kt = 0; kt < 4; kt++){
      const float* p = Wb + kt*32 + g*8;
      acc = mfma16(af[kt], cvt8(*(const float4*)p, *(const float4*)(p+4)), acc);
    }
    int j = jt*16 + la;
    #pragma unroll
    for (int rr = 0; rr < 4; rr++){
      int row = rbase + g*4 + rr;
      int R = blk*64 + row;
      pre5[R*128 + j] = acc[rr] + b5s[j];
    }
  }
}

// ---------------- K2 ----------------
__global__ __launch_bounds__(256) void k2_pre(
    const int* __restrict__ itseq, const float* __restrict__ Eit,
    const float* __restrict__ AL,
    const float* __restrict__ W2, const float* __restrict__ W3,
    const float* __restrict__ W4,
    const float* __restrict__ b2, const float* __restrict__ b3,
    const float* __restrict__ b4,
    float* __restrict__ pre23, float* __restrict__ pre4)
{
  __shared__ __bf16 inA[64*384];
  __shared__ int obase[64];
  __shared__ float b2s[128], b3s[128], b4s[128];
  const int tid = threadIdx.x, blk = blockIdx.x;
  if (tid < 128){ b2s[tid]=b2[tid]; b3s[tid]=b3[tid]; b4s[tid]=b4[tid]; }
  { // vectorized staging: 12 x (float4-pair -> bf16x8); 8-groups never
    // straddle the 128/256 region boundaries (8-aligned starts).
    int r = tid >> 2, seg = tid & 3;
    int R = blk*64 + r;
    bool valid = (R < 4064);
    int b_ = valid ? (R / 127) : 0, tau = valid ? (R % 127) : 0;
    if (seg == 0) obase[r] = valid ? (b_*127 + tau) : -1;
    int itv = valid ? itseq[b_*128 + tau] : 0;
    const float* alm = AL + (size_t)(b_*128 + tau)*128 - 128;  // row tau-1
    const float* ei  = Eit + (size_t)itv*128;
    const float* alc = AL + (size_t)(b_*128 + tau)*128;
    #pragma unroll
    for (int i8 = 0; i8 < 12; i8++){
      int col0 = seg*96 + i8*8;
      bf16x8 v;
      bool z = (!valid) || (col0 < 128 && tau == 0);
      if (z){
        #pragma unroll
        for (int i = 0; i < 8; i++) v[i] = (__bf16)0.f;
      } else {
        const float* src = (col0 < 128) ? (alm + col0)
                         : (col0 < 256) ? (ei + col0 - 128)
                                        : (alc + col0 - 256);
        v = cvt8(*(const float4*)src, *(const float4*)(src+4));
      }
      *(bf16x8*)&inA[(r*384 + col0) ^ ((r&7)<<3)] = v;
    }
  }
  __syncthreads();
  const int w = tid >> 6, lane = tid & 63;
  const int la = lane & 15, g = lane >> 4;
  const int rbase = w*16;
  bf16x8 af[12];
  #pragma unroll
  for (int kt = 0; kt < 12; kt++){
    int idx = ((rbase+la)*384 + kt*32 + g*8) ^ ((la&7)<<3);
    af[kt] = *(const bf16x8*)&inA[idx];
  }
  for (int jt = 0; jt < 16; jt++){
    f32x4 acc = {0.f,0.f,0.f,0.f};
    int j = jt*16 + la;
    const float* Wb = (j < 128) ? (W2 + j*512) : (W3 + (j-128)*512);
    #pragma unroll
    for (int kt = 0; kt < 12; kt++){
      const float* p = Wb + kt*32 + g*8;
      acc = mfma16(af[kt], cvt8(*(const float4*)p, *(const float4*)(p+4)), acc);
    }
    float bias = (j < 128) ? b2s[j] : b3s[j-128];
    #pragma unroll
    for (int rr = 0; rr < 4; rr++){
      int row = rbase + g*4 + rr;
      int ob = obase[row];
      if (ob >= 0) pre23[ob*256 + j] = acc[rr] + bias;
    }
  }
  for (int jt = 0; jt < 8; jt++){
    f32x4 acc = {0.f,0.f,0.f,0.f};
    int j = jt*16 + la;
    const float* Wb = W4 + j*384 + 256;
    #pragma unroll
    for (int kk = 0; kk < 4; kk++){
      const float* p = Wb + kk*32 + g*8;
      acc = mfma16(af[4+kk], cvt8(*(const float4*)p, *(const float4*)(p+4)), acc);
    }
    #pragma unroll
    for (int rr = 0; rr < 4; rr++){
      int row = rbase + g*4 + rr;
      int ob = obase[row];
      if (ob >= 0) pre4[ob*128 + j] = acc[rr] + b4s[j];
    }
  }
}

// ---------------- K3: scan, 32 blocks x 512 threads (round-7, frozen) -------
// LDS floats: hB bf16 2x32768 = 32768 f | htb0[2][128] 256 | htb1[2][128] 256 |
//   LGb 128 | LGh(bf16) 64 | qeb[3][256] 768 | p23L[2][256] 512 |
//   p4L[2][128] 256 | qsl(int) 128 => 35136 f = 140544 B
#define SCAN_LDS_BYTES (35136*4)

__global__ __launch_bounds__(512, 2) void lpkt_scan(
    const float* __restrict__ qmat, const int* __restrict__ qseq,
    const float* __restrict__ h0,
    const float* __restrict__ W2, const float* __restrict__ W3,
    const float* __restrict__ W4,
    const float* __restrict__ pre23, const float* __restrict__ pre4,
    float* __restrict__ hist)
{
  extern __shared__ float lds[];
  __bf16* hB   = (__bf16*)lds;            // 2 x subtiled 256x128
  float*  htb0 = lds + 32768;             // [2][128]
  float*  htb1 = lds + 33024;             // [2][128]
  float*  LGb  = lds + 33280;             // fp32 LG
  __bf16* LGh  = (__bf16*)(lds + 33408);  // bf16 LG
  float*  qeb  = lds + 33472;             // [3][256]
  float*  p23L = lds + 34240;             // [2][256]
  float*  p4L  = lds + 34752;             // [2][128]
  int*    qsl  = (int*)(lds + 35008);

  const int tid  = threadIdx.x;
  const int b    = blockIdx.x;
  const int lane = tid & 63;
  const int w    = tid >> 6;           // 8 waves
  const int la   = lane & 15, g = lane >> 4;
  const int jq   = w & 3;              // j-quarter of k-dim outputs
  const int ch   = w >> 2;             // column half (128 columns)

  // ---- persistent register weight fragments (MFMA-A -> AGPR-friendly) ----
  bf16x8 af[2][4];                     // W4h rows (jq*2+jj)*16+la
  bf16x8 af4l[2][4];                   // W4l rows (jq*2+jj)*16+la
  #pragma unroll
  for (int jj = 0; jj < 2; jj++){
    #pragma unroll
    for (int kt = 0; kt < 4; kt++){
      const float* ph = W4 + ((jq*2+jj)*16+la)*384 + kt*32 + g*8;
      const float* pl = W4 + ((jq*2+jj)*16+la)*384 + 128 + kt*32 + g*8;
      af[jj][kt]   = cvt8(*(const float4*)ph, *(const float4*)(ph+4));
      af4l[jj][kt] = cvt8(*(const float4*)pl, *(const float4*)(pl+4));
    }
  }
  bf16x8 af23[2][4];                   // W2h tile w, W3h tile w
  #pragma unroll
  for (int kt = 0; kt < 4; kt++){
    const float* p2 = W2 + (w*16+la)*512 + 384 + kt*32 + g*8;
    const float* p3 = W3 + (w*16+la)*512 + 384 + kt*32 + g*8;
    af23[0][kt] = cvt8(*(const float4*)p2, *(const float4*)(p2+4));
    af23[1][kt] = cvt8(*(const float4*)p3, *(const float4*)(p3+4));
  }

  // ---- precomputed LDS element bases (buffer 0; parity adds HBUF) ----
  // subtiled: elem(c,k) -> ((c>>4)*16 + (k>>3))*128 + (c&15)*8 + (k&7)
  int rb[8], wb[8];
  #pragma unroll
  for (int cg = 0; cg < 8; cg++){
    const int cblk = ch*8 + cg;          // c>>4 for c = ch*128+cg*16+la
    rb[cg] = cblk*2048 + g*128 + la*8;                          // + kt*512
    wb[cg] = cblk*2048 + jq*512 + (g>>1)*128 + la*8 + (g&1)*4;  // + jj*256
  }

  // ---- init staging ----
  if (tid < 128) qsl[tid] = qseq[b*128 + tid];
  __syncthreads();
  const float* pre23b = pre23 + b*127*256;
  const float* pre4b  = pre4  + b*127*128;
  if (tid < 64)       *(float4*)&qeb[tid*4] = *(const float4*)(qmat + (size_t)qsl[0]*256 + tid*4);
  else if (tid < 128) *(float4*)&qeb[256 + (tid-64)*4] = *(const float4*)(qmat + (size_t)qsl[1]*256 + (tid-64)*4);
  else if (tid < 192) *(float4*)&p23L[(tid-128)*4] = *(const float4*)(pre23b + (tid-128)*4);
  else if (tid < 224) *(float4*)&p4L[(tid-192)*4]  = *(const float4*)(pre4b  + (tid-192)*4);

  // h state -> registers (fp32, D-layout) + bf16 shadow buffer 0
  float4 hreg[8][2];
  #pragma unroll
  for (int cg = 0; cg < 8; cg++){
    const int c_ = ch*128 + cg*16 + la;
    #pragma unroll
    for (int jj = 0; jj < 2; jj++){
      const int k0 = (jq*2+jj)*16 + g*4;
      float4 v = *(const float4*)(h0 + c_*128 + k0);
      hreg[cg][jj] = v;
      bf16x4 hb; hb[0]=(__bf16)v.x; hb[1]=(__bf16)v.y; hb[2]=(__bf16)v.z; hb[3]=(__bf16)v.w;
      *(bf16x4*)&hB[wb[cg] + jj*256] = hb;
    }
  }
  __syncthreads();
  // htilde0 = sum_c qe0[c] * h0[c][:]  (register accum + DPP reduce, split store)
  {
    f32x4 r0 = {0.f,0.f,0.f,0.f}, r1 = {0.f,0.f,0.f,0.f};
    #pragma unroll
    for (int cg = 0; cg < 8; cg++){
      const int c_ = ch*128 + cg*16 + la;
      float q = qeb[c_];
      float4 h0v = hreg[cg][0], h1v = hreg[cg][1];
      r0[0] += q*h0v.x; r0[1] += q*h0v.y; r0[2] += q*h0v.z; r0[3] += q*h0v.w;
      r1[0] += q*h1v.x; r1[1] += q*h1v.y; r1[2] += q*h1v.z; r1[3] += q*h1v.w;
    }
    red16(r0); red16(r1);
    if (la == 15){
      float4 s0 = {r0[0],r0[1],r0[2],r0[3]};
      float4 s1 = {r1[0],r1[1],r1[2],r1[3]};
      *(float4*)&htb0[ch*128 + jq*32 + g*4]      = s0;
      *(float4*)&htb0[ch*128 + jq*32 + 16 + g*4] = s1;
    }
  }
  __syncthreads();

  int i0 = 0, i1 = 1, i2 = 2;          // qe triple-buffer rotation

  for (int tau = 0; tau < 127; tau++){
    float* htc = (tau & 1) ? htb1 : htb0;       // [2][128] partials
    float* htn = (tau & 1) ? htb0 : htb1;
    float* qec = qeb + i0*256;
    float* qen = qeb + i1*256;
    float* qep = qeb + i2*256;
    const float* p23c = p23L + (tau & 1)*256;
    const float* p4c  = p4L  + (tau & 1)*128;
    const int roff = (tau & 1) ? HBUF : 0;
    const int woff = (tau & 1) ? 0 : HBUF;

    // ---- P0: m23 via MFMA (hi/lo), LG on all lanes ----
    {
      bf16x8 xh[4], xl[4];
      #pragma unroll
      for (int kt = 0; kt < 4; kt++){
        int k0 = kt*32 + g*8;
        float4 a0 = *(const float4*)&htc[k0];
        float4 a1 = *(const float4*)&htc[k0+4];
        float4 b0 = *(const float4*)&htc[128 + k0];
        float4 b1v = *(const float4*)&htc[128 + k0+4];
        a0.x += b0.x; a0.y += b0.y; a0.z += b0.z; a0.w += b0.w;
        a1.x += b1v.x; a1.y += b1v.y; a1.z += b1v.z; a1.w += b1v.w;
        mk_hilo(a0, a1, xh[kt], xl[kt]);
      }
      f32x4 aLh = {0.f,0.f,0.f,0.f}, aLl = {0.f,0.f,0.f,0.f};
      f32x4 aGh = {0.f,0.f,0.f,0.f}, aGl = {0.f,0.f,0.f,0.f};
      #pragma unroll
      for (int kt = 0; kt < 4; kt++){
        aLh = mfma16(af23[0][kt], xh[kt], aLh);
        aLl = mfma16(af23[0][kt], xl[kt], aLl);
        aGh = mfma16(af23[1][kt], xh[kt], aGh);
        aGl = mfma16(af23[1][kt], xl[kt], aGl);
      }
      float4 lp4 = *(const float4*)&p23c[w*16 + g*4];
      float4 gp4 = *(const float4*)&p23c[128 + w*16 + g*4];
      float4 LG4;
      LG4.x = sigmf(aGh[0]+aGl[0]+gp4.x) * sigmf(2.f*(aLh[0]+aLl[0]+lp4.x));
      LG4.y = sigmf(aGh[1]+aGl[1]+gp4.y) * sigmf(2.f*(aLh[1]+aLl[1]+lp4.y));
      LG4.z = sigmf(aGh[2]+aGl[2]+gp4.z) * sigmf(2.f*(aLh[2]+aLl[2]+lp4.z));
      LG4.w = sigmf(aGh[3]+aGl[3]+gp4.w) * sigmf(2.f*(aLh[3]+aLl[3]+lp4.w));
      if (la == 0){
        *(float4*)&LGb[w*16 + g*4] = LG4;
        bf16x4 lgp;
        lgp[0]=(__bf16)LG4.x; lgp[1]=(__bf16)LG4.y;
        lgp[2]=(__bf16)LG4.z; lgp[3]=(__bf16)LG4.w;
        *(bf16x4*)&LGh[w*16 + g*4] = lgp;
      }
    }
    __syncthreads();                                    // Bb

    // ---- MAIN ----
    // prefetch issue + hist store (hidden under MFMA phase)
    float4 pf23, pf4, pfqe;
    const bool dopf = (tau < 126);
    const bool do23 = dopf && (tid < 64);
    const bool do4  = dopf && (tid >= 64) && (tid < 96);
    const bool doqe = dopf && (tid >= 448);
    if (do23) pf23 = *(const float4*)(pre23b + (tau+1)*256 + tid*4);
    if (do4)  pf4  = *(const float4*)(pre4b  + (tau+1)*128 + (tid-64)*4);
    if (doqe) pfqe = *(const float4*)(qmat + (size_t)qsl[tau+2]*256 + (tid-448)*4);
    if (tau > 0 && tid >= 96 && tid < 128){
      int i = (tid - 96)*4;
      float4 v0 = *(const float4*)&htc[i];
      float4 v1 = *(const float4*)&htc[128 + i];
      float4 v = {v0.x+v1.x, v0.y+v1.y, v0.z+v1.z, v0.w+v1.w};
      *(float4*)(hist + ((size_t)b*127 + (tau-1))*128 + i) = v;
    }

    // z = W4l @ LG + pre4, in-register (rows aligned with update k0)
    float4 z4[2];
    {
      bf16x8 lh[4];
      #pragma unroll
      for (int kt = 0; kt < 4; kt++)
        lh[kt] = *(const bf16x8*)&LGh[kt*32 + g*8];
      #pragma unroll
      for (int jj = 0; jj < 2; jj++){
        f32x4 az = {0.f,0.f,0.f,0.f};
        #pragma unroll
        for (int kt = 0; kt < 4; kt++)
          az = mfma16(af4l[jj][kt], lh[kt], az);
        float4 zp = *(const float4*)&p4c[(jq*2+jj)*16 + g*4];
        z4[jj].x = az[0]+zp.x; z4[jj].y = az[1]+zp.y;
        z4[jj].z = az[2]+zp.z; z4[jj].w = az[3]+zp.w;
      }
    }
    float4 lg4[2];
    #pragma unroll
    for (int jj = 0; jj < 2; jj++)
      lg4[jj] = *(const float4*)&LGb[(jq*2+jj)*16 + g*4];

    // software-pipelined bfv: load cg+1 while computing cg
    bf16x8 bA[4], bB[4];
    {
      const int base = rb[0] + roff;
      #pragma unroll
      for (int kt = 0; kt < 4; kt++) bA[kt] = *(const bf16x8*)&hB[base + kt*512];
    }
    f32x4 r0 = {0.f,0.f,0.f,0.f}, r1 = {0.f,0.f,0.f,0.f};
    #pragma unroll
    for (int cg = 0; cg < 8; cg++){
      const bf16x8* cur = (cg & 1) ? bB : bA;
      bf16x8*       nxt = (cg & 1) ? bA : bB;
      if (cg < 7){
        const int base = rb[cg+1] + roff;
        #pragma unroll
        for (int kt = 0; kt < 4; kt++) nxt[kt] = *(const bf16x8*)&hB[base + kt*512];
      }
      const int c_ = ch*128 + cg*16 + la;
      const float qe_t = qec[c_], qe_n = qen[c_];
      const int wbase = wb[cg] + woff;
      #pragma unroll
      for (int jj = 0; jj < 2; jj++){
        f32x4 acc = {0.f,0.f,0.f,0.f};
        #pragma unroll
        for (int kt = 0; kt < 4; kt++)
          acc = mfma16(af[jj][kt], cur[kt], acc);
        float4 hp = hreg[cg][jj];
        float4 hn;
        hn.x = qe_t*lg4[jj].x + sigmf(acc[0] + z4[jj].x)*hp.x;
        hn.y = qe_t*lg4[jj].y + sigmf(acc[1] + z4[jj].y)*hp.y;
        hn.z = qe_t*lg4[jj].z + sigmf(acc[2] + z4[jj].z)*hp.z;
        hn.w = qe_t*lg4[jj].w + sigmf(acc[3] + z4[jj].w)*hp.w;
        hreg[cg][jj] = hn;
        bf16x4 hb; hb[0]=(__bf16)hn.x; hb[1]=(__bf16)hn.y; hb[2]=(__bf16)hn.z; hb[3]=(__bf16)hn.w;
        *(bf16x4*)&hB[wbase + jj*256] = hb;
        f32x4& r = (jj == 0) ? r0 : r1;
        r[0] += qe_n*hn.x; r[1] += qe_n*hn.y;
        r[2] += qe_n*hn.z; r[3] += qe_n*hn.w;
      }
    }
    // h_tilde: DPP reduce over 16 la-lanes, split plain stores (no atomics)
    red16(r0); red16(r1);
    if (la == 15){
      float4 s0 = {r0[0],r0[1],r0[2],r0[3]};
      float4 s1 = {r1[0],r1[1],r1[2],r1[3]};
      *(float4*)&htn[ch*128 + jq*32 + g*4]      = s0;
      *(float4*)&htn[ch*128 + jq*32 + 16 + g*4] = s1;
    }
    // prefetch writes (different buffers than those read this step)
    if (do23) *(float4*)&p23L[((tau+1)&1)*256 + tid*4] = pf23;
    if (do4)  *(float4*)&p4L[((tau+1)&1)*128 + (tid-64)*4] = pf4;
    if (doqe) *(float4*)&qep[(tid-448)*4] = pfqe;       // qe[tau+2]
    __syncthreads();                                    // B2
    int t_ = i0; i0 = i1; i1 = i2; i2 = t_;
  }

  // epilogue: store final h_tilde (htn of tau=126 lives in htb1)
  if (tid < 32){
    int i = tid*4;
    float4 v0 = *(const float4*)&htb1[i];
    float4 v1 = *(const float4*)&htb1[128 + i];
    float4 v = {v0.x+v1.x, v0.y+v1.y, v0.z+v1.z, v0.w+v1.w};
    *(float4*)(hist + ((size_t)b*127 + 126)*128 + i) = v;
  }
}

// ---------------- K4: y as MFMA GEMM (64 blocks x 256 threads) ----------------
__global__ __launch_bounds__(256) void k4_gemm(
    const float* __restrict__ hist, const float* __restrict__ pre5,
    const float* __restrict__ W5, float* __restrict__ out)
{
  __shared__ __bf16 xs[64*128];
  const int tid = threadIdx.x, blk = blockIdx.x;
  { // stage h_tilde rows (bf16, swizzled); s==0 rows -> zeros
    int r = tid >> 2, seg = tid & 3;
    int R = blk*64 + r;
    int s = R & 127, b = R >> 7;
    const float* src = hist + ((size_t)b*127 + (s-1))*128;
    #pragma unroll
    for (int i8 = 0; i8 < 4; i8++){
      int col0 = seg*32 + i8*8;
      bf16x8 v;
      if (s > 0){
        v = cvt8(*(const float4*)(src + col0), *(const float4*)(src + col0 + 4));
      } else {
        #pragma unroll
        for (int i = 0; i < 8; i++) v[i] = (__bf16)0.f;
      }
      *(bf16x8*)&xs[(r*128 + col0) ^ ((r&7)<<3)] = v;
    }
  }
  __syncthreads();
  const int w = tid >> 6, lane = tid & 63;
  const int la = lane & 15, g = lane >> 4;
  const int rbase = w*16;
  bf16x8 af[4];
  #pragma unroll
  for (int kt = 0; kt < 4; kt++){
    int idx = ((rbase+la)*128 + kt*32 + g*8) ^ ((la&7)<<3);
    af[kt] = *(const bf16x8*)&xs[idx];
  }
  f32x4 ysum = {0.f,0.f,0.f,0.f};
  for (int jt = 0; jt < 8; jt++){
    f32x4 acc = {0.f,0.f,0.f,0.f};
    const float* Wb = W5 + (jt*16+la)*256 + 128;  // W5h rows
    #pragma unroll
    for (int kt = 0; kt < 4; kt++){
      const float* p = Wb + kt*32 + g*8;
      acc = mfma16(af[kt], cvt8(*(const float4*)p, *(const float4*)(p+4)), acc);
    }
    int j = jt*16 + la;
    #pragma unroll
    for (int rr = 0; rr < 4; rr++){
      int R = blk*64 + rbase + g*4 + rr;
      ysum[rr] += sigmf(acc[rr] + pre5[(size_t)R*128 + j]);
    }
  }
  red16(ysum);                     // sum over the 16 la-lanes (cols)
  if (la == 15){
    #pragma unroll
    for (int rr = 0; rr < 4; rr++){
      int R = blk*64 + rbase + g*4 + rr;
      out[R] = ((R & 127) == 0) ? 0.f : ysum[rr] * (1.f/128.f);
    }
  }
}

// ---------------- host launch ----------------
extern "C" void kernel_launch(void* const* d_in, const int* in_sizes, int n_in,
                              void* d_out, int out_size, void* d_ws, size_t ws_size,
                              hipStream_t stream) {
  const int*   qseq  = (const int*)  d_in[0];
  const int*   itseq = (const int*)  d_in[1];
  const int*   utseq = (const int*)  d_in[2];
  const float* corr  = (const float*)d_in[3];
  const float* Eq    = (const float*)d_in[4];
  const float* Eit   = (const float*)d_in[5];
  const float* Eut   = (const float*)d_in[6];
  const float* qmat  = (const float*)d_in[7];
  const float* h0    = (const float*)d_in[8];
  const float* W1    = (const float*)d_in[9];
  const float* b1    = (const float*)d_in[10];
  const float* W2    = (const float*)d_in[11];
  const float* b2    = (const float*)d_in[12];
  const float* W3    = (const float*)d_in[13];
  const float* b3    = (const float*)d_in[14];
  const float* W4    = (const float*)d_in[15];
  const float* b4    = (const float*)d_in[16];
  const float* W5    = (const float*)d_in[17];
  const float* b5    = (const float*)d_in[18];
  float* out = (float*)d_out;

  float* ws    = (float*)d_ws;
  float* AL    = ws;                    // 4096*128 ; reused as hist after k2
  float* hist  = ws;                    // 32*127*128 <= AL size
  float* pre5  = ws + 524288;           // 4096*128
  float* pre23 = ws + 1048576;          // 4064*256
  float* pre4  = ws + 2088960;          // 4064*128

  (void)hipFuncSetAttribute(reinterpret_cast<const void*>(&lpkt_scan),
                            hipFuncAttributeMaxDynamicSharedMemorySize,
                            SCAN_LDS_BYTES);

  hipLaunchKernelGGL(k1_al, dim3(64), dim3(256), 0, stream,
                     qseq, utseq, corr, Eq, Eut, W1, b1, W5, b5, AL, pre5);
  hipLaunchKernelGGL(k2_pre, dim3(64), dim3(256), 0, stream,
                     itseq, Eit, AL, W2, W3, W4, b2, b3, b4, pre23, pre4);
  hipLaunchKernelGGL(lpkt_scan, dim3(32), dim3(512), SCAN_LDS_BYTES, stream,
                     qmat, qseq, h0, W2, W3, W4, pre23, pre4, hist);
  hipLaunchKernelGGL(k4_gemm, dim3(64), dim3(256), 0, stream,
                     hist, pre5, W5, out);
}